// Round 2
// baseline (507.693 us; speedup 1.0000x reference)
//
#include <hip/hip_runtime.h>
#include <hip/hip_bf16.h>
#include <hip/hip_cooperative_groups.h>
#include <stdint.h>

namespace cg = cooperative_groups;

#define S_LEN 1024
#define BATCH 2
#define DM    768
#define NH    12
#define HD    64
#define W1    32
#define WIN   65
#define NQKV  2304
#define M_TOT 2048

typedef unsigned short u16;
typedef __attribute__((ext_vector_type(4))) float f4;
typedef __attribute__((ext_vector_type(4))) unsigned short us4;
typedef __attribute__((ext_vector_type(8))) unsigned short ushort8;
typedef __attribute__((ext_vector_type(8))) __bf16 bf16x8;
typedef __attribute__((ext_vector_type(4))) float f32x4;

__device__ inline float bf2f(u16 x) {
    union { unsigned u; float f; } z;
    z.u = ((unsigned)x) << 16;
    return z.f;
}
__device__ inline u16 f2bf(float x) {
    union { float f; unsigned u; } z;
    z.f = x;
    unsigned r = z.u + 0x7FFF + ((z.u >> 16) & 1);   // RNE
    return (u16)(r >> 16);
}

// async global->LDS, 16B per lane. LDS dest is wave-uniform base + lane*16.
__device__ __forceinline__ void g2l16(const u16* g, u16* l) {
    __builtin_amdgcn_global_load_lds(
        (const __attribute__((address_space(1))) unsigned int*)g,
        (__attribute__((address_space(3))) unsigned int*)l, 16, 0, 0);
}

// ===========================================================================
// FUSED single cooperative kernel: prep -> QKV GEMM -> attn+pool -> fc.
// 576 blocks x 256 threads, 48 KB LDS union -> 3 blocks/CU (co-resident:
// 576 <= 768). Removes 3 inter-kernel dispatch boundaries (launch latency +
// device cache barriers) — the round-1 post-mortem's candidate for the
// ~100 us gap between kernel-side cost model (~20 us) and measured 119 us.
// Phase math is identical to the verified round-1 kernels (absmax 1.22e-4).
// ===========================================================================
__global__ __launch_bounds__(256, 3) void fused_all(
    const float* __restrict__ X,
    const float* __restrict__ Wq, const float* __restrict__ Wk,
    const float* __restrict__ Wv,
    const float* __restrict__ bq, const float* __restrict__ bk,
    const float* __restrict__ bv,
    const float* __restrict__ Wfc, const float* __restrict__ bfc,
    u16* __restrict__ Xb, u16* __restrict__ Wt,
    u16* __restrict__ Q, u16* __restrict__ K, u16* __restrict__ Vt,
    float* __restrict__ partial, float* __restrict__ out) {

    __shared__ __align__(16) union {
        float ftile[64][69];                                   // prep W transpose
        struct { u16 As[2][128 * 64]; u16 Bs[2][64 * 64]; } g; // GEMM dbuf (48 KB)
        struct {                                               // 2 attn units (41 KB)
            u16 vt[2][64][104];
            u16 pl[2][2][16][104];
            float pr[2][2][64];
        } a;
        struct { float red[4][64]; float ps[DM]; } f;          // fc
    } sm;

    const int bid = blockIdx.x;     // 0..575
    const int t = threadIdx.x;
    cg::grid_group grid = cg::this_grid();

    // ---------------- Phase 0: prep (1200 units over 576 blocks) -----------
    for (int u = bid; u < 1200; u += 576) {
        if (u < 768) {
            // X f32 -> Xb bf16
            const long base = (long)u * 2048 + t * 8;
            f4 a = *(const f4*)&X[base];
            f4 b = *(const f4*)&X[base + 4];
            float v[8] = {a.x, a.y, a.z, a.w, b.x, b.y, b.z, b.w};
            ushort8 h;
            #pragma unroll
            for (int j = 0; j < 8; ++j) h[j] = f2bf(v[j]);
            *(ushort8*)&Xb[base] = h;
        } else {
            // weight transpose+concat -> Wt bf16 [n][k]
            const int tw = u - 768;             // 0..431
            const int n0 = (tw % 36) * 64;      // 0..2240
            const int k0 = (tw / 36) * 64;      // 0..704
            const int sel = n0 / DM;
            const int nl0 = n0 % DM;
            const float* W = (sel == 0) ? Wq : ((sel == 1) ? Wk : Wv);
            const int r = t >> 3;               // 0..31
            const int cg8 = t & 7;              // 0..7

            #pragma unroll
            for (int p = 0; p < 2; ++p) {
                int rr = r + p * 32;            // source row (k)
                long gb = (long)(k0 + rr) * DM + nl0 + cg8 * 8;
                *(f4*)&sm.ftile[rr][cg8 * 8]     = *(const f4*)&W[gb];
                *(f4*)&sm.ftile[rr][cg8 * 8 + 4] = *(const f4*)&W[gb + 4];
            }
            __syncthreads();
            #pragma unroll
            for (int p = 0; p < 2; ++p) {
                int rn = r + p * 32;            // output row (n)
                ushort8 h;
                #pragma unroll
                for (int jj = 0; jj < 8; ++jj)
                    h[jj] = f2bf(sm.ftile[cg8 * 8 + jj][rn]);
                *(ushort8*)&Wt[(long)(n0 + rn) * DM + k0 + cg8 * 8] = h;
            }
        }
    }

    __threadfence();
    grid.sync();

    // ---------------- Phase 1: QKV GEMM (576 tiles, 1 per block) -----------
    {
        const int xcd = bid & 7;
        const int local = bid >> 3;
        const int mt = (xcd & 1) * 8 + (local & 7);
        const int nt = (xcd >> 1) * 9 + (local >> 3);
        const int m0 = mt * 128;
        const int n0 = nt * 64;
        const int lane = t & 63;
        const int w = t >> 6;
        const int wm = w * 32;
        const int lrow = lane & 15;
        const int lq = lane >> 4;

        // pre-swizzled global sources (XOR swizzle on source, LDS linear)
        const u16* gA[4];
        const u16* gB[2];
        #pragma unroll
        for (int p = 0; p < 4; ++p) {
            int slot = p * 256 + t;
            int row = slot >> 3;
            int skc = (slot & 7) ^ (row & 7);
            gA[p] = Xb + (long)(m0 + row) * DM + skc * 8;
        }
        #pragma unroll
        for (int p = 0; p < 2; ++p) {
            int slot = p * 256 + t;
            int row = slot >> 3;
            int skc = (slot & 7) ^ (row & 7);
            gB[p] = Wt + (long)(n0 + row) * DM + skc * 8;
        }

#define STAGE(buf)                                                          \
    do {                                                                    \
        _Pragma("unroll")                                                   \
        for (int p = 0; p < 4; ++p)                                         \
            g2l16(gA[p], &sm.g.As[buf][(p * 256 + w * 64) * 8]);            \
        _Pragma("unroll")                                                   \
        for (int p = 0; p < 2; ++p)                                         \
            g2l16(gB[p], &sm.g.Bs[buf][(p * 256 + w * 64) * 8]);            \
        _Pragma("unroll")                                                   \
        for (int p = 0; p < 4; ++p) gA[p] += 64;                            \
        _Pragma("unroll")                                                   \
        for (int p = 0; p < 2; ++p) gB[p] += 64;                            \
    } while (0)

        const f32x4 fzero = {0.f, 0.f, 0.f, 0.f};
        f32x4 acc[2][4];
        #pragma unroll
        for (int i = 0; i < 2; ++i)
            #pragma unroll
            for (int j = 0; j < 4; ++j) acc[i][j] = fzero;

        STAGE(0);
        __syncthreads();    // drains vmcnt(0): tile 0 resident

        #pragma unroll
        for (int ks = 0; ks < 12; ++ks) {
            const int cb = ks & 1;
            if (ks < 11) STAGE(cb ^ 1);     // async prefetch overlaps compute
            #pragma unroll
            for (int kh = 0; kh < 2; ++kh) {
                const int c = kh * 4 + lq;
                bf16x8 ah[2], bh[4];
                #pragma unroll
                for (int i = 0; i < 2; ++i) {
                    int ar = wm + i * 16 + lrow;
                    ah[i] = *(const bf16x8*)&sm.g.As[cb][(ar * 8 + (c ^ (ar & 7))) * 8];
                }
                #pragma unroll
                for (int j = 0; j < 4; ++j) {
                    int br = j * 16 + lrow;
                    bh[j] = *(const bf16x8*)&sm.g.Bs[cb][(br * 8 + (c ^ (br & 7))) * 8];
                }
                #pragma unroll
                for (int i = 0; i < 2; ++i)
                    #pragma unroll
                    for (int j = 0; j < 4; ++j)
                        acc[i][j] = __builtin_amdgcn_mfma_f32_16x16x32_bf16(
                            ah[i], bh[j], acc[i][j], 0, 0, 0);
            }
            if (ks < 11) __syncthreads();
        }
#undef STAGE

        const int region = n0 / DM;     // 0=Q, 1=K, 2=V
        const int nc0 = n0 % DM;
        const float* bias = (region == 0) ? bq : ((region == 1) ? bk : bv);

        if (region < 2) {
            u16* Out = (region == 0) ? Q : K;
            #pragma unroll
            for (int j = 0; j < 4; ++j) {
                int col = nc0 + j * 16 + lrow;
                float bval = bias[col];
                #pragma unroll
                for (int i = 0; i < 2; ++i) {
                    int row = m0 + wm + i * 16 + lq * 4;
                    #pragma unroll
                    for (int r = 0; r < 4; ++r)
                        Out[(long)(row + r) * DM + col] = f2bf(acc[i][j][r] + bval);
                }
            }
        } else {
            const int h = nc0 >> 6;
            #pragma unroll
            for (int j = 0; j < 4; ++j) {
                int dloc = j * 16 + lrow;
                float bval = bias[nc0 + dloc];
                #pragma unroll
                for (int i = 0; i < 2; ++i) {
                    int row = m0 + wm + i * 16 + lq * 4;
                    int b = row >> 10, sl = row & 1023;
                    us4 pk;
                    #pragma unroll
                    for (int r = 0; r < 4; ++r) pk[r] = f2bf(acc[i][j][r] + bval);
                    *(us4*)&Vt[(((long)(b * NH + h) * 64 + dloc) << 10) + sl] = pk;
                }
            }
        }
    }

    __threadfence();
    grid.sync();

    // ---------------- Phase 2: attention (768 units, 2 per block) ----------
    if (bid < 384) {
        const int half = t >> 7;            // which 128-thread unit
        const int tl = t & 127;
        const int unit = bid * 2 + half;    // 0..767
        const int b = unit / 384;
        const int rem = unit % 384;
        const int h = rem >> 5;
        const int sblk = rem & 31;
        const int s0 = sblk * 32;
        const int k0 = s0 - 32;

        // stage V^T window: 64 d x 96 keys
        const u16* vtg = Vt + ((size_t)(b * NH + h) * 64) * 1024;
        #pragma unroll
        for (int it = 0; it < 6; ++it) {
            int slot = it * 128 + tl;       // 0..767
            int d = slot / 12, kc = slot % 12;
            int kbase = k0 + kc * 8;
            if (kbase >= 0 && kbase + 7 < S_LEN) {
                *(ushort8*)&sm.a.vt[half][d][kc * 8] =
                    *(const ushort8*)&vtg[d * 1024 + kbase];
            } else {
                #pragma unroll
                for (int j = 0; j < 8; ++j) {
                    int kk = kbase + j;
                    int kcl = kk < 0 ? 0 : (kk > S_LEN - 1 ? S_LEN - 1 : kk);
                    sm.a.vt[half][d][kc * 8 + j] = vtg[d * 1024 + kcl];
                }
            }
        }
        __syncthreads();

        const int w = tl >> 6, lane = tl & 63;
        const int cl = lane & 15, q = lane >> 4;

        const f32x4 fzero = {0.f, 0.f, 0.f, 0.f};
        f32x4 accS[6];
        #pragma unroll
        for (int n = 0; n < 6; ++n) accS[n] = fzero;

        const long qrow = (long)(b * S_LEN + s0 + w * 16 + cl);
        bf16x8 aq[2];
        #pragma unroll
        for (int ks = 0; ks < 2; ++ks)
            aq[ks] = *(const bf16x8*)&Q[qrow * DM + h * HD + ks * 32 + q * 8];
        #pragma unroll
        for (int n = 0; n < 6; ++n) {
            int key = k0 + n * 16 + cl;
            int kcl = key < 0 ? 0 : (key > S_LEN - 1 ? S_LEN - 1 : key);
            long ka = (long)(b * S_LEN + kcl) * DM + h * HD;
            #pragma unroll
            for (int ks = 0; ks < 2; ++ks) {
                bf16x8 bk8 = *(const bf16x8*)&K[ka + ks * 32 + q * 8];
                accS[n] = __builtin_amdgcn_mfma_f32_16x16x32_bf16(aq[ks], bk8, accS[n], 0, 0, 0);
            }
        }

        float l4[4] = {0.f, 0.f, 0.f, 0.f};
        #pragma unroll
        for (int n = 0; n < 6; ++n) {
            int key = k0 + n * 16 + cl;
            #pragma unroll
            for (int r = 0; r < 4; ++r) {
                int s = s0 + w * 16 + q * 4 + r;
                bool valid = (key >= s - W1) && (key <= s + W1) && (key >= 0) && (key < S_LEN);
                float p = valid ? __expf(accS[n][r] * 0.125f) : 0.f;
                accS[n][r] = p;
                l4[r] += p;
            }
        }
        #pragma unroll
        for (int m = 1; m <= 8; m <<= 1)
            #pragma unroll
            for (int r = 0; r < 4; ++r) l4[r] += __shfl_xor(l4[r], m, 64);

        #pragma unroll
        for (int n = 0; n < 6; ++n)
            #pragma unroll
            for (int r = 0; r < 4; ++r)
                sm.a.pl[half][w][q * 4 + r][n * 16 + cl] = f2bf(accS[n][r]);

        f32x4 accO[4];
        #pragma unroll
        for (int n = 0; n < 4; ++n) accO[n] = fzero;
        bf16x8 ap[3];
        #pragma unroll
        for (int ks = 0; ks < 3; ++ks)
            ap[ks] = *(const bf16x8*)&sm.a.pl[half][w][cl][ks * 32 + q * 8];
        #pragma unroll
        for (int n = 0; n < 4; ++n)
            #pragma unroll
            for (int ks = 0; ks < 3; ++ks) {
                bf16x8 bv8 = *(const bf16x8*)&sm.a.vt[half][n * 16 + cl][ks * 32 + q * 8];
                accO[n] = __builtin_amdgcn_mfma_f32_16x16x32_bf16(ap[ks], bv8, accO[n], 0, 0, 0);
            }

        float rcp4[4];
        #pragma unroll
        for (int r = 0; r < 4; ++r) rcp4[r] = 1.0f / l4[r];
        #pragma unroll
        for (int n = 0; n < 4; ++n) {
            float pp = 0.f;
            #pragma unroll
            for (int r = 0; r < 4; ++r) pp += accO[n][r] * rcp4[r];
            pp += __shfl_xor(pp, 16, 64);
            pp += __shfl_xor(pp, 32, 64);
            if (q == 0) sm.a.pr[half][w][n * 16 + cl] = pp;
        }
        __syncthreads();
        if (tl < 64) {
            long pb = (((long)(b * NH + h) * 32) + sblk) * 64 + tl;
            partial[pb] = sm.a.pr[half][0][tl] + sm.a.pr[half][1][tl];
        }
    }

    __threadfence();
    grid.sync();

    // ---------------- Phase 3: fc (24 units) -------------------------------
    if (bid < 24) {
        const int nb = bid % 12;
        const int bb = bid / 12;

        for (int d = t; d < DM; d += 256) {
            const float* pp = partial + ((long)(bb * NH + (d >> 6)) * 32) * 64 + (d & 63);
            float s = 0.f;
            #pragma unroll
            for (int sb = 0; sb < 32; ++sb) s += pp[sb * 64];
            sm.f.ps[d] = s;
        }
        __syncthreads();

        const int nn = t & 63;
        const int dg = t >> 6;
        const int n = nb * 64 + nn;
        float s = 0.f;
        for (int d = dg * 192; d < dg * 192 + 192; ++d)
            s += sm.f.ps[d] * Wfc[(long)d * DM + n];
        sm.f.red[dg][nn] = s;
        __syncthreads();
        if (t < 64) {
            float sum = sm.f.red[0][t] + sm.f.red[1][t] + sm.f.red[2][t] + sm.f.red[3][t];
            sum = sum * (1.0f / (float)S_LEN) + bfc[nb * 64 + t];
            sum = sum > 0.f ? sum : 0.f;
            out[bb * DM + nb * 64 + t] = sum;
        }
    }
}

// ===========================================================================
// Fallback path: the verified round-1 four-kernel pipeline (in case
// hipLaunchCooperativeKernel is rejected under graph capture).
// ===========================================================================
__global__ __launch_bounds__(256) void prep(
    const float* __restrict__ X,
    const float* __restrict__ Wq, const float* __restrict__ Wk,
    const float* __restrict__ Wv,
    u16* __restrict__ Xb, u16* __restrict__ Wt) {
    __shared__ float tile[64][69];
    const int t = threadIdx.x;
    const int bid = blockIdx.x;

    if (bid < 768) {
        const long base = (long)bid * 2048 + t * 8;
        f4 a = *(const f4*)&X[base];
        f4 b = *(const f4*)&X[base + 4];
        float v[8] = {a.x, a.y, a.z, a.w, b.x, b.y, b.z, b.w};
        ushort8 h;
        #pragma unroll
        for (int j = 0; j < 8; ++j) h[j] = f2bf(v[j]);
        *(ushort8*)&Xb[base] = h;
    } else {
        const int tw = bid - 768;
        const int n0 = (tw % 36) * 64;
        const int k0 = (tw / 36) * 64;
        const int sel = n0 / DM;
        const int nl0 = n0 % DM;
        const float* W = (sel == 0) ? Wq : ((sel == 1) ? Wk : Wv);
        const int r = t >> 3;
        const int cg8 = t & 7;

        #pragma unroll
        for (int p = 0; p < 2; ++p) {
            int rr = r + p * 32;
            long gb = (long)(k0 + rr) * DM + nl0 + cg8 * 8;
            *(f4*)&tile[rr][cg8 * 8]     = *(const f4*)&W[gb];
            *(f4*)&tile[rr][cg8 * 8 + 4] = *(const f4*)&W[gb + 4];
        }
        __syncthreads();
        #pragma unroll
        for (int p = 0; p < 2; ++p) {
            int rn = r + p * 32;
            ushort8 h;
            #pragma unroll
            for (int jj = 0; jj < 8; ++jj)
                h[jj] = f2bf(tile[cg8 * 8 + jj][rn]);
            *(ushort8*)&Wt[(long)(n0 + rn) * DM + k0 + cg8 * 8] = h;
        }
    }
}

__global__ __launch_bounds__(256) void qkv_gemm_mfma(
    const u16* __restrict__ Xb, const u16* __restrict__ Wt,
    const float* __restrict__ bq, const float* __restrict__ bk,
    const float* __restrict__ bv,
    u16* __restrict__ Q, u16* __restrict__ K, u16* __restrict__ Vt) {
    __shared__ u16 As[2][128 * 64];
    __shared__ u16 Bs[2][64 * 64];

    const int bid = blockIdx.x;
    const int xcd = bid & 7;
    const int local = bid >> 3;
    const int mt = (xcd & 1) * 8 + (local & 7);
    const int nt = (xcd >> 1) * 9 + (local >> 3);
    const int m0 = mt * 128;
    const int n0 = nt * 64;
    const int t = threadIdx.x;
    const int lane = t & 63;
    const int w = t >> 6;
    const int wm = w * 32;
    const int lrow = lane & 15;
    const int lq = lane >> 4;

    const u16* gA[4];
    const u16* gB[2];
    #pragma unroll
    for (int p = 0; p < 4; ++p) {
        int slot = p * 256 + t;
        int row = slot >> 3;
        int skc = (slot & 7) ^ (row & 7);
        gA[p] = Xb + (long)(m0 + row) * DM + skc * 8;
    }
    #pragma unroll
    for (int p = 0; p < 2; ++p) {
        int slot = p * 256 + t;
        int row = slot >> 3;
        int skc = (slot & 7) ^ (row & 7);
        gB[p] = Wt + (long)(n0 + row) * DM + skc * 8;
    }

#define STAGE(buf)                                                          \
    do {                                                                    \
        _Pragma("unroll")                                                   \
        for (int p = 0; p < 4; ++p)                                         \
            g2l16(gA[p], &As[buf][(p * 256 + w * 64) * 8]);                 \
        _Pragma("unroll")                                                   \
        for (int p = 0; p < 2; ++p)                                         \
            g2l16(gB[p], &Bs[buf][(p * 256 + w * 64) * 8]);                 \
        _Pragma("unroll")                                                   \
        for (int p = 0; p < 4; ++p) gA[p] += 64;                            \
        _Pragma("unroll")                                                   \
        for (int p = 0; p < 2; ++p) gB[p] += 64;                            \
    } while (0)

    const f32x4 fzero = {0.f, 0.f, 0.f, 0.f};
    f32x4 acc[2][4];
    #pragma unroll
    for (int i = 0; i < 2; ++i)
        #pragma unroll
        for (int j = 0; j < 4; ++j) acc[i][j] = fzero;

    STAGE(0);
    __syncthreads();

    #pragma unroll
    for (int ks = 0; ks < 12; ++ks) {
        const int cb = ks & 1;
        if (ks < 11) STAGE(cb ^ 1);
        #pragma unroll
        for (int kh = 0; kh < 2; ++kh) {
            const int c = kh * 4 + lq;
            bf16x8 ah[2], bh[4];
            #pragma unroll
            for (int i = 0; i < 2; ++i) {
                int ar = wm + i * 16 + lrow;
                ah[i] = *(const bf16x8*)&As[cb][(ar * 8 + (c ^ (ar & 7))) * 8];
            }
            #pragma unroll
            for (int j = 0; j < 4; ++j) {
                int br = j * 16 + lrow;
                bh[j] = *(const bf16x8*)&Bs[cb][(br * 8 + (c ^ (br & 7))) * 8];
            }
            #pragma unroll
            for (int i = 0; i < 2; ++i)
                #pragma unroll
                for (int j = 0; j < 4; ++j)
                    acc[i][j] = __builtin_amdgcn_mfma_f32_16x16x32_bf16(
                        ah[i], bh[j], acc[i][j], 0, 0, 0);
        }
        if (ks < 11) __syncthreads();
    }
#undef STAGE

    const int region = n0 / DM;
    const int nc0 = n0 % DM;
    const float* bias = (region == 0) ? bq : ((region == 1) ? bk : bv);

    if (region < 2) {
        u16* Out = (region == 0) ? Q : K;
        #pragma unroll
        for (int j = 0; j < 4; ++j) {
            int col = nc0 + j * 16 + lrow;
            float bval = bias[col];
            #pragma unroll
            for (int i = 0; i < 2; ++i) {
                int row = m0 + wm + i * 16 + lq * 4;
                #pragma unroll
                for (int r = 0; r < 4; ++r)
                    Out[(long)(row + r) * DM + col] = f2bf(acc[i][j][r] + bval);
            }
        }
    } else {
        const int h = nc0 >> 6;
        #pragma unroll
        for (int j = 0; j < 4; ++j) {
            int dloc = j * 16 + lrow;
            float bval = bias[nc0 + dloc];
            #pragma unroll
            for (int i = 0; i < 2; ++i) {
                int row = m0 + wm + i * 16 + lq * 4;
                int b = row >> 10, sl = row & 1023;
                us4 pk;
                #pragma unroll
                for (int r = 0; r < 4; ++r) pk[r] = f2bf(acc[i][j][r] + bval);
                *(us4*)&Vt[(((long)(b * NH + h) * 64 + dloc) << 10) + sl] = pk;
            }
        }
    }
}

__global__ __launch_bounds__(128) void attn_pool_mfma(
    const u16* __restrict__ Q, const u16* __restrict__ K,
    const u16* __restrict__ Vt, float* __restrict__ partial) {
    __shared__ u16 vt[64][104];
    __shared__ u16 pl[2][16][104];
    __shared__ float pr[2][64];
    const int b = blockIdx.z, h = blockIdx.y;
    const int s0 = blockIdx.x * 32;
    const int t = threadIdx.x;
    const int k0 = s0 - 32;

    const u16* vtg = Vt + ((size_t)(b * NH + h) * 64) * 1024;
    #pragma unroll
    for (int it = 0; it < 6; ++it) {
        int slot = it * 128 + t;
        int d = slot / 12, kc = slot % 12;
        int kbase = k0 + kc * 8;
        if (kbase >= 0 && kbase + 7 < S_LEN) {
            *(ushort8*)&vt[d][kc * 8] = *(const ushort8*)&vtg[d * 1024 + kbase];
        } else {
            #pragma unroll
            for (int j = 0; j < 8; ++j) {
                int kk = kbase + j;
                int kcl = kk < 0 ? 0 : (kk > S_LEN - 1 ? S_LEN - 1 : kk);
                vt[d][kc * 8 + j] = vtg[d * 1024 + kcl];
            }
        }
    }
    __syncthreads();

    const int w = t >> 6, lane = t & 63;
    const int cl = lane & 15, q = lane >> 4;

    const f32x4 fzero = {0.f, 0.f, 0.f, 0.f};
    f32x4 accS[6];
    #pragma unroll
    for (int n = 0; n < 6; ++n) accS[n] = fzero;

    const long qrow = (long)(b * S_LEN + s0 + w * 16 + cl);
    bf16x8 aq[2];
    #pragma unroll
    for (int ks = 0; ks < 2; ++ks)
        aq[ks] = *(const bf16x8*)&Q[qrow * DM + h * HD + ks * 32 + q * 8];
    #pragma unroll
    for (int n = 0; n < 6; ++n) {
        int key = k0 + n * 16 + cl;
        int kcl = key < 0 ? 0 : (key > S_LEN - 1 ? S_LEN - 1 : key);
        long ka = (long)(b * S_LEN + kcl) * DM + h * HD;
        #pragma unroll
        for (int ks = 0; ks < 2; ++ks) {
            bf16x8 bk8 = *(const bf16x8*)&K[ka + ks * 32 + q * 8];
            accS[n] = __builtin_amdgcn_mfma_f32_16x16x32_bf16(aq[ks], bk8, accS[n], 0, 0, 0);
        }
    }

    float l4[4] = {0.f, 0.f, 0.f, 0.f};
    #pragma unroll
    for (int n = 0; n < 6; ++n) {
        int key = k0 + n * 16 + cl;
        #pragma unroll
        for (int r = 0; r < 4; ++r) {
            int s = s0 + w * 16 + q * 4 + r;
            bool valid = (key >= s - W1) && (key <= s + W1) && (key >= 0) && (key < S_LEN);
            float p = valid ? __expf(accS[n][r] * 0.125f) : 0.f;
            accS[n][r] = p;
            l4[r] += p;
        }
    }
    #pragma unroll
    for (int m = 1; m <= 8; m <<= 1)
        #pragma unroll
        for (int r = 0; r < 4; ++r) l4[r] += __shfl_xor(l4[r], m, 64);

    #pragma unroll
    for (int n = 0; n < 6; ++n)
        #pragma unroll
        for (int r = 0; r < 4; ++r)
            pl[w][q * 4 + r][n * 16 + cl] = f2bf(accS[n][r]);

    f32x4 accO[4];
    #pragma unroll
    for (int n = 0; n < 4; ++n) accO[n] = fzero;
    bf16x8 ap[3];
    #pragma unroll
    for (int ks = 0; ks < 3; ++ks)
        ap[ks] = *(const bf16x8*)&pl[w][cl][ks * 32 + q * 8];
    #pragma unroll
    for (int n = 0; n < 4; ++n)
        #pragma unroll
        for (int ks = 0; ks < 3; ++ks) {
            bf16x8 bv8 = *(const bf16x8*)&vt[n * 16 + cl][ks * 32 + q * 8];
            accO[n] = __builtin_amdgcn_mfma_f32_16x16x32_bf16(ap[ks], bv8, accO[n], 0, 0, 0);
        }

    float rcp4[4];
    #pragma unroll
    for (int r = 0; r < 4; ++r) rcp4[r] = 1.0f / l4[r];
    #pragma unroll
    for (int n = 0; n < 4; ++n) {
        float pp = 0.f;
        #pragma unroll
        for (int r = 0; r < 4; ++r) pp += accO[n][r] * rcp4[r];
        pp += __shfl_xor(pp, 16, 64);
        pp += __shfl_xor(pp, 32, 64);
        if (q == 0) pr[w][n * 16 + cl] = pp;
    }
    __syncthreads();
    if (t < 64) {
        long pb = (((long)(b * NH + h) * 32) + blockIdx.x) * 64 + t;
        partial[pb] = pr[0][t] + pr[1][t];
    }
}

__global__ __launch_bounds__(256) void fc_relu_f(
    const float* __restrict__ partial, const float* __restrict__ Wfc,
    const float* __restrict__ bfc, float* __restrict__ out) {
    __shared__ float red[4][64];
    __shared__ float ps[768];
    const int t = threadIdx.x;
    const int nb = blockIdx.x % 12;
    const int bb = blockIdx.x / 12;

    for (int d = t; d < DM; d += 256) {
        const float* pp = partial + ((long)(bb * NH + (d >> 6)) * 32) * 64 + (d & 63);
        float s = 0.f;
        #pragma unroll
        for (int sb = 0; sb < 32; ++sb) s += pp[sb * 64];
        ps[d] = s;
    }
    __syncthreads();

    const int nn = t & 63;
    const int dg = t >> 6;
    const int n = nb * 64 + nn;
    float s = 0.f;
    for (int d = dg * 192; d < dg * 192 + 192; ++d)
        s += ps[d] * Wfc[(long)d * DM + n];
    red[dg][nn] = s;
    __syncthreads();
    if (t < 64) {
        float sum = red[0][t] + red[1][t] + red[2][t] + red[3][t];
        sum = sum * (1.0f / (float)S_LEN) + bfc[nb * 64 + t];
        sum = sum > 0.f ? sum : 0.f;
        out[bb * DM + nb * 64 + t] = sum;
    }
}

// ---------------------------------------------------------------------------
extern "C" void kernel_launch(void* const* d_in, const int* in_sizes, int n_in,
                              void* d_out, int out_size, void* d_ws, size_t ws_size,
                              hipStream_t stream) {
    const float* X   = (const float*)d_in[0];
    const float* Wq  = (const float*)d_in[1];
    const float* bq  = (const float*)d_in[2];
    const float* Wk  = (const float*)d_in[3];
    const float* bk  = (const float*)d_in[4];
    const float* Wv  = (const float*)d_in[5];
    const float* bv  = (const float*)d_in[6];
    const float* Wfc = (const float*)d_in[7];
    const float* bfc = (const float*)d_in[8];

    char* ws = (char*)d_ws;
    const size_t SZ_XB = (size_t)M_TOT * DM * 2;              // 3,145,728
    const size_t SZ_WB = (size_t)NQKV * DM * 2;               // 3,538,944
    u16* Xb = (u16*)(ws);
    u16* Wt = (u16*)(ws + SZ_XB);
    u16* Qp = (u16*)(ws + SZ_XB + SZ_WB);
    u16* Kp = (u16*)(ws + 2 * SZ_XB + SZ_WB);
    u16* Vt = (u16*)(ws + 3 * SZ_XB + SZ_WB);
    float* partial = (float*)(ws + 4 * SZ_XB + SZ_WB);        // [2][12][32][64] f32
    float* outp = (float*)d_out;

    void* args[] = {
        (void*)&X, (void*)&Wq, (void*)&Wk, (void*)&Wv,
        (void*)&bq, (void*)&bk, (void*)&bv,
        (void*)&Wfc, (void*)&bfc,
        (void*)&Xb, (void*)&Wt, (void*)&Qp, (void*)&Kp, (void*)&Vt,
        (void*)&partial, (void*)&outp
    };
    hipError_t e = hipLaunchCooperativeKernel(
        (const void*)fused_all, dim3(576), dim3(256), args, 0, stream);
    if (e != hipSuccess) {
        (void)hipGetLastError();
        prep<<<1200, 256, 0, stream>>>(X, Wq, Wk, Wv, Xb, Wt);
        qkv_gemm_mfma<<<576, 256, 0, stream>>>(Xb, Wt, bq, bk, bv, Qp, Kp, Vt);
        attn_pool_mfma<<<dim3(32, NH, BATCH), 128, 0, stream>>>(Qp, Kp, Vt, partial);
        fc_relu_f<<<24, 256, 0, stream>>>(partial, Wfc, bfc, outp);
    }
}

// Round 4
// 130.003 us; speedup vs baseline: 3.9052x; 3.9052x over previous
//
#include <hip/hip_runtime.h>
#include <hip/hip_bf16.h>
#include <stdint.h>

#define S_LEN 1024
#define BATCH 2
#define DM    768
#define NH    12
#define HD    64
#define W1    32
#define WIN   65
#define NQKV  2304
#define M_TOT 2048

typedef unsigned short u16;
typedef __attribute__((ext_vector_type(4))) float f4;
typedef __attribute__((ext_vector_type(4))) unsigned short us4;
typedef __attribute__((ext_vector_type(8))) unsigned short ushort8;
typedef __attribute__((ext_vector_type(8))) __bf16 bf16x8;
typedef __attribute__((ext_vector_type(4))) float f32x4;

__device__ inline u16 f2bf(float x) {
    union { float f; unsigned u; } z;
    z.f = x;
    unsigned r = z.u + 0x7FFF + ((z.u >> 16) & 1);   // RNE
    return (u16)(r >> 16);
}

// async global->LDS, 16B per lane. LDS dest is wave-uniform base + lane*16.
__device__ __forceinline__ void g2l16(const u16* g, u16* l) {
    __builtin_amdgcn_global_load_lds(
        (const __attribute__((address_space(1))) unsigned int*)g,
        (__attribute__((address_space(3))) unsigned int*)l, 16, 0, 0);
}

// ---------------------------------------------------------------------------
// Kernel 1: prep. Blocks [0,768): X f32 -> Xb bf16. Blocks [768,1200):
// transpose+concat weights -> Wt bf16 [n][k].
// ---------------------------------------------------------------------------
__global__ __launch_bounds__(256) void prep(
    const float* __restrict__ X,
    const float* __restrict__ Wq, const float* __restrict__ Wk,
    const float* __restrict__ Wv,
    u16* __restrict__ Xb, u16* __restrict__ Wt) {
    __shared__ float tile[64][69];
    const int t = threadIdx.x;
    const int bid = blockIdx.x;

    if (bid < 768) {
        const long base = (long)bid * 2048 + t * 8;
        f4 a = *(const f4*)&X[base];
        f4 b = *(const f4*)&X[base + 4];
        float v[8] = {a.x, a.y, a.z, a.w, b.x, b.y, b.z, b.w};
        ushort8 h;
        #pragma unroll
        for (int j = 0; j < 8; ++j) h[j] = f2bf(v[j]);
        *(ushort8*)&Xb[base] = h;
    } else {
        const int tw = bid - 768;           // 0..431
        const int n0 = (tw % 36) * 64;      // 0..2240
        const int k0 = (tw / 36) * 64;      // 0..704
        const int sel = n0 / DM;
        const int nl0 = n0 % DM;
        const float* W = (sel == 0) ? Wq : ((sel == 1) ? Wk : Wv);
        const int r = t >> 3;               // 0..31
        const int cg8 = t & 7;              // 0..7

        #pragma unroll
        for (int p = 0; p < 2; ++p) {
            int rr = r + p * 32;            // source row (k)
            long gb = (long)(k0 + rr) * DM + nl0 + cg8 * 8;
            *(f4*)&tile[rr][cg8 * 8]     = *(const f4*)&W[gb];
            *(f4*)&tile[rr][cg8 * 8 + 4] = *(const f4*)&W[gb + 4];
        }
        __syncthreads();
        #pragma unroll
        for (int p = 0; p < 2; ++p) {
            int rn = r + p * 32;            // output row (n)
            ushort8 h;
            #pragma unroll
            for (int jj = 0; jj < 8; ++jj)
                h[jj] = f2bf(tile[cg8 * 8 + jj][rn]);
            *(ushort8*)&Wt[(long)(n0 + rn) * DM + k0 + cg8 * 8] = h;
        }
    }
}

// ---------------------------------------------------------------------------
// Kernel 2: fused QKV GEMM, plain bf16 MFMA (round-1 verified structure).
// 128x64 tile (MxN), BK=64, 576 blocks, 2x4 XCD swizzle.
// Double-buffered LDS + global_load_lds (16B) with XOR swizzle applied to
// the GLOBAL source address (LDS lane-linear); 2-phase prefetch.
// ---------------------------------------------------------------------------
__global__ __launch_bounds__(256) void qkv_gemm_mfma(
    const u16* __restrict__ Xb, const u16* __restrict__ Wt,
    const float* __restrict__ bq, const float* __restrict__ bk,
    const float* __restrict__ bv,
    u16* __restrict__ Q, u16* __restrict__ K, u16* __restrict__ Vt) {
    __shared__ u16 As[2][128 * 64];
    __shared__ u16 Bs[2][64 * 64];

    const int bid = blockIdx.x;
    const int xcd = bid & 7;
    const int local = bid >> 3;
    const int mt = (xcd & 1) * 8 + (local & 7);
    const int nt = (xcd >> 1) * 9 + (local >> 3);
    const int m0 = mt * 128;
    const int n0 = nt * 64;
    const int t = threadIdx.x;
    const int lane = t & 63;
    const int w = t >> 6;
    const int wm = w * 32;
    const int lrow = lane & 15;
    const int lq = lane >> 4;

    const u16* gA[4];
    const u16* gB[2];
    #pragma unroll
    for (int p = 0; p < 4; ++p) {
        int slot = p * 256 + t;
        int row = slot >> 3;
        int skc = (slot & 7) ^ (row & 7);
        gA[p] = Xb + (long)(m0 + row) * DM + skc * 8;
    }
    #pragma unroll
    for (int p = 0; p < 2; ++p) {
        int slot = p * 256 + t;
        int row = slot >> 3;
        int skc = (slot & 7) ^ (row & 7);
        gB[p] = Wt + (long)(n0 + row) * DM + skc * 8;
    }

#define STAGE(buf)                                                          \
    do {                                                                    \
        _Pragma("unroll")                                                   \
        for (int p = 0; p < 4; ++p)                                         \
            g2l16(gA[p], &As[buf][(p * 256 + w * 64) * 8]);                 \
        _Pragma("unroll")                                                   \
        for (int p = 0; p < 2; ++p)                                         \
            g2l16(gB[p], &Bs[buf][(p * 256 + w * 64) * 8]);                 \
        _Pragma("unroll")                                                   \
        for (int p = 0; p < 4; ++p) gA[p] += 64;                            \
        _Pragma("unroll")                                                   \
        for (int p = 0; p < 2; ++p) gB[p] += 64;                            \
    } while (0)

    const f32x4 fzero = {0.f, 0.f, 0.f, 0.f};
    f32x4 acc[2][4];
    #pragma unroll
    for (int i = 0; i < 2; ++i)
        #pragma unroll
        for (int j = 0; j < 4; ++j) acc[i][j] = fzero;

    STAGE(0);
    __syncthreads();

    #pragma unroll
    for (int ks = 0; ks < 12; ++ks) {
        const int cb = ks & 1;
        if (ks < 11) STAGE(cb ^ 1);
        #pragma unroll
        for (int kh = 0; kh < 2; ++kh) {
            const int c = kh * 4 + lq;
            bf16x8 ah[2], bh[4];
            #pragma unroll
            for (int i = 0; i < 2; ++i) {
                int ar = wm + i * 16 + lrow;
                ah[i] = *(const bf16x8*)&As[cb][(ar * 8 + (c ^ (ar & 7))) * 8];
            }
            #pragma unroll
            for (int j = 0; j < 4; ++j) {
                int br = j * 16 + lrow;
                bh[j] = *(const bf16x8*)&Bs[cb][(br * 8 + (c ^ (br & 7))) * 8];
            }
            #pragma unroll
            for (int i = 0; i < 2; ++i)
                #pragma unroll
                for (int j = 0; j < 4; ++j)
                    acc[i][j] = __builtin_amdgcn_mfma_f32_16x16x32_bf16(
                        ah[i], bh[j], acc[i][j], 0, 0, 0);
        }
        if (ks < 11) __syncthreads();
    }
#undef STAGE

    const int region = n0 / DM;
    const int nc0 = n0 % DM;
    const float* bias = (region == 0) ? bq : ((region == 1) ? bk : bv);

    if (region < 2) {
        u16* Out = (region == 0) ? Q : K;
        #pragma unroll
        for (int j = 0; j < 4; ++j) {
            int col = nc0 + j * 16 + lrow;
            float bval = bias[col];
            #pragma unroll
            for (int i = 0; i < 2; ++i) {
                int row = m0 + wm + i * 16 + lq * 4;
                #pragma unroll
                for (int r = 0; r < 4; ++r)
                    Out[(long)(row + r) * DM + col] = f2bf(acc[i][j][r] + bval);
            }
        }
    } else {
        const int h = nc0 >> 6;
        #pragma unroll
        for (int j = 0; j < 4; ++j) {
            int dloc = j * 16 + lrow;
            float bval = bias[nc0 + dloc];
            #pragma unroll
            for (int i = 0; i < 2; ++i) {
                int row = m0 + wm + i * 16 + lq * 4;
                int b = row >> 10, sl = row & 1023;
                us4 pk;
                #pragma unroll
                for (int r = 0; r < 4; ++r) pk[r] = f2bf(acc[i][j][r] + bval);
                *(us4*)&Vt[(((long)(b * NH + h) * 64 + dloc) << 10) + sl] = pk;
            }
        }
    }
}

// ---------------------------------------------------------------------------
// Kernel 3: MFMA flash attention + pooled partial.
// vs round 1: V^T is NOT staged in LDS (L2-resident, 128 KB/head): the PV
// B-operand is loaded directly from global Vt[b][h][d][s] (contiguous in s).
// Only the 2 edge s-blocks take a per-element clamped path; clamped keys
// multiply P=0, so contributions are exactly 0 — math identical.
// LDS drops 20.5 KB -> 7.2 KB; one barrier and the staging loop removed.
// ---------------------------------------------------------------------------
__global__ __launch_bounds__(128) void attn_pool_mfma(
    const u16* __restrict__ Q, const u16* __restrict__ K,
    const u16* __restrict__ Vt, float* __restrict__ partial) {
    __shared__ u16 pl[2][16][104];     // per-wave P: [wave][query row][key]
    __shared__ float pr[2][64];        // per-wave pooled partials
    const int b = blockIdx.z, h = blockIdx.y;
    const int bx = blockIdx.x;
    const int s0 = bx * 32;
    const int t = threadIdx.x;
    const int k0 = s0 - 32;

    const u16* vtg = Vt + ((size_t)(b * NH + h) * 64) * 1024;
    const int w = t >> 6, lane = t & 63;
    const int cl = lane & 15, q = lane >> 4;

    // ---- scores: S = Q . K^T (6 key-tiles of 16) ----
    const f32x4 fzero = {0.f, 0.f, 0.f, 0.f};
    f32x4 accS[6];
    #pragma unroll
    for (int n = 0; n < 6; ++n) accS[n] = fzero;

    const long qrow = (long)(b * S_LEN + s0 + w * 16 + cl);
    bf16x8 aq[2];
    #pragma unroll
    for (int ks = 0; ks < 2; ++ks)
        aq[ks] = *(const bf16x8*)&Q[qrow * DM + h * HD + ks * 32 + q * 8];
    #pragma unroll
    for (int n = 0; n < 6; ++n) {
        int key = k0 + n * 16 + cl;
        int kcl = key < 0 ? 0 : (key > S_LEN - 1 ? S_LEN - 1 : key);
        long ka = (long)(b * S_LEN + kcl) * DM + h * HD;
        #pragma unroll
        for (int ks = 0; ks < 2; ++ks) {
            bf16x8 bk8 = *(const bf16x8*)&K[ka + ks * 32 + q * 8];
            accS[n] = __builtin_amdgcn_mfma_f32_16x16x32_bf16(aq[ks], bk8, accS[n], 0, 0, 0);
        }
    }

    // ---- softmax (unnormalized) in C-layout: col=cl(key), row=q*4+r ----
    float l4[4] = {0.f, 0.f, 0.f, 0.f};
    #pragma unroll
    for (int n = 0; n < 6; ++n) {
        int key = k0 + n * 16 + cl;
        #pragma unroll
        for (int r = 0; r < 4; ++r) {
            int s = s0 + w * 16 + q * 4 + r;
            bool valid = (key >= s - W1) && (key <= s + W1) && (key >= 0) && (key < S_LEN);
            float p = valid ? __expf(accS[n][r] * 0.125f) : 0.f;
            accS[n][r] = p;
            l4[r] += p;
        }
    }
    #pragma unroll
    for (int m = 1; m <= 8; m <<= 1)
        #pragma unroll
        for (int r = 0; r < 4; ++r) l4[r] += __shfl_xor(l4[r], m, 64);

    // ---- P -> LDS in A-layout (same-wave round trip) ----
    #pragma unroll
    for (int n = 0; n < 6; ++n)
        #pragma unroll
        for (int r = 0; r < 4; ++r)
            pl[w][q * 4 + r][n * 16 + cl] = f2bf(accS[n][r]);

    // ---- O = P . V: V^T direct from global (contiguous in key) ----
    f32x4 accO[4];
    #pragma unroll
    for (int n = 0; n < 4; ++n) accO[n] = fzero;
    bf16x8 ap[3];
    #pragma unroll
    for (int ks = 0; ks < 3; ++ks)
        ap[ks] = *(const bf16x8*)&pl[w][cl][ks * 32 + q * 8];

    const bool edge = (bx == 0) || (bx == 31);
    #pragma unroll
    for (int n = 0; n < 4; ++n) {
        const u16* vrow = &vtg[(size_t)(n * 16 + cl) * 1024];
        #pragma unroll
        for (int ks = 0; ks < 3; ++ks) {
            int kb = k0 + ks * 32 + q * 8;
            bf16x8 bv8;
            if (!edge) {
                bv8 = *(const bf16x8*)&vrow[kb];
            } else {
                union { ushort8 u; bf16x8 bfv; } cvt;
                #pragma unroll
                for (int j = 0; j < 8; ++j) {
                    int kk = kb + j;
                    int kcl = kk < 0 ? 0 : (kk > S_LEN - 1 ? S_LEN - 1 : kk);
                    cvt.u[j] = vrow[kcl];
                }
                bv8 = cvt.bfv;
            }
            accO[n] = __builtin_amdgcn_mfma_f32_16x16x32_bf16(ap[ks], bv8, accO[n], 0, 0, 0);
        }
    }

    // ---- normalize rows, pool over the wave's 16 queries, LDS reduce ----
    float rcp4[4];
    #pragma unroll
    for (int r = 0; r < 4; ++r) rcp4[r] = 1.0f / l4[r];
    #pragma unroll
    for (int n = 0; n < 4; ++n) {
        float pp = 0.f;
        #pragma unroll
        for (int r = 0; r < 4; ++r) pp += accO[n][r] * rcp4[r];
        pp += __shfl_xor(pp, 16, 64);
        pp += __shfl_xor(pp, 32, 64);
        if (q == 0) pr[w][n * 16 + cl] = pp;
    }
    __syncthreads();
    if (t < 64) {
        long pb = (((long)(b * NH + h) * 32) + bx) * 64 + t;
        partial[pb] = pr[0][t] + pr[1][t];
    }
}

// ---------------------------------------------------------------------------
// Kernel 4: out = relu((sum_sblk partial)/S @ Wfc + bfc) -> f32.
// 24 blocks = (batch, col64).
// ---------------------------------------------------------------------------
__global__ __launch_bounds__(256) void fc_relu_f(
    const float* __restrict__ partial, const float* __restrict__ Wfc,
    const float* __restrict__ bfc, float* __restrict__ out) {
    __shared__ float red[4][64];
    __shared__ float ps[768];
    const int t = threadIdx.x;
    const int nb = blockIdx.x % 12;     // col tile
    const int bb = blockIdx.x / 12;     // batch

    for (int d = t; d < DM; d += 256) {
        const float* pp = partial + ((long)(bb * NH + (d >> 6)) * 32) * 64 + (d & 63);
        float s = 0.f;
        #pragma unroll
        for (int sb = 0; sb < 32; ++sb) s += pp[sb * 64];
        ps[d] = s;
    }
    __syncthreads();

    const int nn = t & 63;
    const int dg = t >> 6;              // 0..3
    const int n = nb * 64 + nn;
    float s = 0.f;
    for (int d = dg * 192; d < dg * 192 + 192; ++d)
        s += ps[d] * Wfc[(long)d * DM + n];
    red[dg][nn] = s;
    __syncthreads();
    if (t < 64) {
        float sum = red[0][t] + red[1][t] + red[2][t] + red[3][t];
        sum = sum * (1.0f / (float)S_LEN) + bfc[nb * 64 + t];
        sum = sum > 0.f ? sum : 0.f;
        out[bb * DM + nb * 64 + t] = sum;
    }
}

// ---------------------------------------------------------------------------
extern "C" void kernel_launch(void* const* d_in, const int* in_sizes, int n_in,
                              void* d_out, int out_size, void* d_ws, size_t ws_size,
                              hipStream_t stream) {
    const float* X   = (const float*)d_in[0];
    const float* Wq  = (const float*)d_in[1];
    const float* bq  = (const float*)d_in[2];
    const float* Wk  = (const float*)d_in[3];
    const float* bk  = (const float*)d_in[4];
    const float* Wv  = (const float*)d_in[5];
    const float* bv  = (const float*)d_in[6];
    const float* Wfc = (const float*)d_in[7];
    const float* bfc = (const float*)d_in[8];

    char* ws = (char*)d_ws;
    const size_t SZ_XB = (size_t)M_TOT * DM * 2;              // 3,145,728
    const size_t SZ_WB = (size_t)NQKV * DM * 2;               // 3,538,944
    u16* Xb = (u16*)(ws);
    u16* Wt = (u16*)(ws + SZ_XB);
    u16* Qp = (u16*)(ws + SZ_XB + SZ_WB);
    u16* Kp = (u16*)(ws + 2 * SZ_XB + SZ_WB);
    u16* Vt = (u16*)(ws + 3 * SZ_XB + SZ_WB);
    float* partial = (float*)(ws + 4 * SZ_XB + SZ_WB);        // [2][12][32][64] f32

    prep<<<1200, 256, 0, stream>>>(X, Wq, Wk, Wv, Xb, Wt);

    qkv_gemm_mfma<<<576, 256, 0, stream>>>(
        Xb, Wt, bq, bk, bv, Qp, Kp, Vt);

    attn_pool_mfma<<<dim3(32, NH, BATCH), 128, 0, stream>>>(
        Qp, Kp, Vt, partial);

    fc_relu_f<<<24, 256, 0, stream>>>(partial, Wfc, bfc, (float*)d_out);
}

// Round 5
// 115.556 us; speedup vs baseline: 4.3935x; 1.1250x over previous
//
#include <hip/hip_runtime.h>
#include <hip/hip_bf16.h>
#include <stdint.h>

#define S_LEN 1024
#define BATCH 2
#define DM    768
#define NH    12
#define HD    64
#define W1    32
#define WIN   65
#define NQKV  2304
#define M_TOT 2048

typedef unsigned short u16;
typedef __attribute__((ext_vector_type(4))) float f4;
typedef __attribute__((ext_vector_type(4))) unsigned short us4;
typedef __attribute__((ext_vector_type(8))) unsigned short ushort8;
typedef __attribute__((ext_vector_type(8))) __bf16 bf16x8;
typedef __attribute__((ext_vector_type(4))) float f32x4;

__device__ inline u16 f2bf(float x) {
    union { float f; unsigned u; } z;
    z.f = x;
    unsigned r = z.u + 0x7FFF + ((z.u >> 16) & 1);   // RNE
    return (u16)(r >> 16);
}

// async global->LDS, 16B per lane. LDS dest is wave-uniform base + lane*16.
__device__ __forceinline__ void g2l16(const u16* g, u16* l) {
    __builtin_amdgcn_global_load_lds(
        (const __attribute__((address_space(1))) unsigned int*)g,
        (__attribute__((address_space(3))) unsigned int*)l, 16, 0, 0);
}

// ---------------------------------------------------------------------------
// Kernel 1: prep. Blocks [0,768): X f32 -> Xb bf16. Blocks [768,1200):
// transpose+concat weights -> Wt bf16 [n][k].
// ---------------------------------------------------------------------------
__global__ __launch_bounds__(256) void prep(
    const float* __restrict__ X,
    const float* __restrict__ Wq, const float* __restrict__ Wk,
    const float* __restrict__ Wv,
    u16* __restrict__ Xb, u16* __restrict__ Wt) {
    __shared__ float tile[64][69];
    const int t = threadIdx.x;
    const int bid = blockIdx.x;

    if (bid < 768) {
        const long base = (long)bid * 2048 + t * 8;
        f4 a = *(const f4*)&X[base];
        f4 b = *(const f4*)&X[base + 4];
        float v[8] = {a.x, a.y, a.z, a.w, b.x, b.y, b.z, b.w};
        ushort8 h;
        #pragma unroll
        for (int j = 0; j < 8; ++j) h[j] = f2bf(v[j]);
        *(ushort8*)&Xb[base] = h;
    } else {
        const int tw = bid - 768;           // 0..431
        const int n0 = (tw % 36) * 64;      // 0..2240
        const int k0 = (tw / 36) * 64;      // 0..704
        const int sel = n0 / DM;
        const int nl0 = n0 % DM;
        const float* W = (sel == 0) ? Wq : ((sel == 1) ? Wk : Wv);
        const int r = t >> 3;               // 0..31
        const int cg8 = t & 7;              // 0..7

        #pragma unroll
        for (int p = 0; p < 2; ++p) {
            int rr = r + p * 32;            // source row (k)
            long gb = (long)(k0 + rr) * DM + nl0 + cg8 * 8;
            *(f4*)&tile[rr][cg8 * 8]     = *(const f4*)&W[gb];
            *(f4*)&tile[rr][cg8 * 8 + 4] = *(const f4*)&W[gb + 4];
        }
        __syncthreads();
        #pragma unroll
        for (int p = 0; p < 2; ++p) {
            int rn = r + p * 32;            // output row (n)
            ushort8 h;
            #pragma unroll
            for (int jj = 0; jj < 8; ++jj)
                h[jj] = f2bf(tile[cg8 * 8 + jj][rn]);
            *(ushort8*)&Wt[(long)(n0 + rn) * DM + k0 + cg8 * 8] = h;
        }
    }
}

// ---------------------------------------------------------------------------
// Kernel 2: fused QKV GEMM, plain bf16 MFMA.
// NEW geometry: 64x96 tile (MxN), 32x24 = 768 blocks = EXACTLY 3 blocks/CU
// (was 576 = 2.25/CU: worst CUs carried 33% extra). 40 KB LDS dbuf (4/CU
// capacity, occupancy unchanged at 12 waves/CU). Same 2-phase gload_lds +
// source-side XOR swizzle; same K accumulation order -> bitwise-identical
// Q/K/Vt. Per-XCD: 4 consecutive m-tiles x all nt => Xb panel 393KB + full
// Wt 3.5MB fits the 4MB XCD L2.
// Region map: nt 0..7 = Q, 8..15 = K, 16..23 = V. 16-wide j-frags start at
// multiples of 16 so they never straddle a 64-wide head boundary.
// ---------------------------------------------------------------------------
__global__ __launch_bounds__(256) void qkv_gemm_mfma(
    const u16* __restrict__ Xb, const u16* __restrict__ Wt,
    const float* __restrict__ bq, const float* __restrict__ bk,
    const float* __restrict__ bv,
    u16* __restrict__ Q, u16* __restrict__ K, u16* __restrict__ Vt) {
    __shared__ u16 As[2][64 * 64];     // 8 KB per buffer
    __shared__ u16 Bs[2][96 * 64];     // 12 KB per buffer

    const int bid = blockIdx.x;         // 0..767
    const int xcd = bid & 7;            // presumed XCD (RR dispatch)
    const int local = bid >> 3;         // 0..95 within XCD
    const int nt = local % 24;          // 0..23
    const int mt = (xcd << 2) + (local / 24);   // 0..31
    const int m0 = mt * 64;
    const int n0 = nt * 96;
    const int t = threadIdx.x;
    const int lane = t & 63;
    const int w = t >> 6;
    const int wm = w * 16;              // wave's M offset (16-row strip)
    const int lrow = lane & 15;
    const int lq = lane >> 4;

    // pre-swizzled global sources (XOR swizzle on source, LDS lane-linear)
    const u16* gA[2];
    const u16* gB[3];
    #pragma unroll
    for (int p = 0; p < 2; ++p) {
        int slot = p * 256 + t;         // 0..511 -> 64 rows x 8 chunks
        int row = slot >> 3;
        int skc = (slot & 7) ^ (row & 7);
        gA[p] = Xb + (long)(m0 + row) * DM + skc * 8;
    }
    #pragma unroll
    for (int p = 0; p < 3; ++p) {
        int slot = p * 256 + t;         // 0..767 -> 96 rows x 8 chunks
        int row = slot >> 3;
        int skc = (slot & 7) ^ (row & 7);
        gB[p] = Wt + (long)(n0 + row) * DM + skc * 8;
    }

#define STAGE(buf)                                                          \
    do {                                                                    \
        _Pragma("unroll")                                                   \
        for (int p = 0; p < 2; ++p)                                         \
            g2l16(gA[p], &As[buf][(p * 256 + w * 64) * 8]);                 \
        _Pragma("unroll")                                                   \
        for (int p = 0; p < 3; ++p)                                         \
            g2l16(gB[p], &Bs[buf][(p * 256 + w * 64) * 8]);                 \
        _Pragma("unroll")                                                   \
        for (int p = 0; p < 2; ++p) gA[p] += 64;                            \
        _Pragma("unroll")                                                   \
        for (int p = 0; p < 3; ++p) gB[p] += 64;                            \
    } while (0)

    const f32x4 fzero = {0.f, 0.f, 0.f, 0.f};
    f32x4 acc[6];
    #pragma unroll
    for (int j = 0; j < 6; ++j) acc[j] = fzero;

    STAGE(0);
    __syncthreads();    // drains vmcnt(0): tile 0 resident

    #pragma unroll
    for (int ks = 0; ks < 12; ++ks) {
        const int cb = ks & 1;
        if (ks < 11) STAGE(cb ^ 1);     // async prefetch overlaps compute
        #pragma unroll
        for (int kh = 0; kh < 2; ++kh) {
            const int c = kh * 4 + lq;
            const int ar = wm + lrow;   // 0..63
            bf16x8 ah = *(const bf16x8*)&As[cb][(ar * 8 + (c ^ (ar & 7))) * 8];
            bf16x8 bh[6];
            #pragma unroll
            for (int j = 0; j < 6; ++j) {
                int br = j * 16 + lrow; // 0..95
                bh[j] = *(const bf16x8*)&Bs[cb][(br * 8 + (c ^ (br & 7))) * 8];
            }
            #pragma unroll
            for (int j = 0; j < 6; ++j)
                acc[j] = __builtin_amdgcn_mfma_f32_16x16x32_bf16(
                    ah, bh[j], acc[j], 0, 0, 0);
        }
        if (ks < 11) __syncthreads();
    }
#undef STAGE

    const int region = n0 / DM;     // 0=Q, 1=K, 2=V
    const int nc0 = n0 % DM;        // 0,96,...,672
    const float* bias = (region == 0) ? bq : ((region == 1) ? bk : bv);
    const int row = m0 + wm + lq * 4;

    if (region < 2) {
        u16* Out = (region == 0) ? Q : K;
        #pragma unroll
        for (int j = 0; j < 6; ++j) {
            int col = nc0 + j * 16 + lrow;
            float bval = bias[col];
            #pragma unroll
            for (int r = 0; r < 4; ++r)
                Out[(long)(row + r) * DM + col] = f2bf(acc[j][r] + bval);
        }
    } else {
        // V: write transposed bf16 Vt[b][h][dloc][s]
        const int b = row >> 10, sl = row & 1023;
        #pragma unroll
        for (int j = 0; j < 6; ++j) {
            int c = nc0 + j * 16 + lrow;    // global V column 0..767
            int h = c >> 6, dloc = c & 63;  // head / in-head dim
            float bval = bias[c];
            us4 pk;
            #pragma unroll
            for (int r = 0; r < 4; ++r) pk[r] = f2bf(acc[j][r] + bval);
            *(us4*)&Vt[(((long)(b * NH + h) * 64 + dloc) << 10) + sl] = pk;
        }
    }
}

// ---------------------------------------------------------------------------
// Kernel 3: MFMA flash attention + pooled partial (round-1 verified: V^T
// STAGED in LDS — round 4 proved direct-global V costs +11 us from exposed
// per-lane scattered load latency inside the PV chain).
// ---------------------------------------------------------------------------
__global__ __launch_bounds__(128) void attn_pool_mfma(
    const u16* __restrict__ Q, const u16* __restrict__ K,
    const u16* __restrict__ Vt, float* __restrict__ partial) {
    __shared__ u16 vt[64][104];        // V^T window: [d][key 96 + pad 8]
    __shared__ u16 pl[2][16][104];     // per-wave P: [wave][query row][key]
    __shared__ float pr[2][64];        // per-wave pooled partials
    const int b = blockIdx.z, h = blockIdx.y;
    const int s0 = blockIdx.x * 32;
    const int t = threadIdx.x;
    const int k0 = s0 - 32;

    // stage V^T window: 64 d x 96 keys = 768 8-elem chunks, 6 iters x 128 thr
    const u16* vtg = Vt + ((size_t)(b * NH + h) * 64) * 1024;
    #pragma unroll
    for (int it = 0; it < 6; ++it) {
        int slot = it * 128 + t;        // 0..767
        int d = slot / 12, kc = slot % 12;
        int kbase = k0 + kc * 8;
        if (kbase >= 0 && kbase + 7 < S_LEN) {
            *(ushort8*)&vt[d][kc * 8] = *(const ushort8*)&vtg[d * 1024 + kbase];
        } else {
            #pragma unroll
            for (int j = 0; j < 8; ++j) {
                int kk = kbase + j;
                int kcl = kk < 0 ? 0 : (kk > S_LEN - 1 ? S_LEN - 1 : kk);
                vt[d][kc * 8 + j] = vtg[d * 1024 + kcl];
            }
        }
    }
    __syncthreads();

    const int w = t >> 6, lane = t & 63;
    const int cl = lane & 15, q = lane >> 4;

    // ---- scores: S = Q . K^T (6 key-tiles of 16) ----
    const f32x4 fzero = {0.f, 0.f, 0.f, 0.f};
    f32x4 accS[6];
    #pragma unroll
    for (int n = 0; n < 6; ++n) accS[n] = fzero;

    const long qrow = (long)(b * S_LEN + s0 + w * 16 + cl);
    bf16x8 aq[2];
    #pragma unroll
    for (int ks = 0; ks < 2; ++ks)
        aq[ks] = *(const bf16x8*)&Q[qrow * DM + h * HD + ks * 32 + q * 8];
    #pragma unroll
    for (int n = 0; n < 6; ++n) {
        int key = k0 + n * 16 + cl;
        int kcl = key < 0 ? 0 : (key > S_LEN - 1 ? S_LEN - 1 : key);
        long ka = (long)(b * S_LEN + kcl) * DM + h * HD;
        #pragma unroll
        for (int ks = 0; ks < 2; ++ks) {
            bf16x8 bk8 = *(const bf16x8*)&K[ka + ks * 32 + q * 8];
            accS[n] = __builtin_amdgcn_mfma_f32_16x16x32_bf16(aq[ks], bk8, accS[n], 0, 0, 0);
        }
    }

    // ---- softmax (unnormalized) in C-layout: col=cl(key), row=q*4+r ----
    float l4[4] = {0.f, 0.f, 0.f, 0.f};
    #pragma unroll
    for (int n = 0; n < 6; ++n) {
        int key = k0 + n * 16 + cl;
        #pragma unroll
        for (int r = 0; r < 4; ++r) {
            int s = s0 + w * 16 + q * 4 + r;
            bool valid = (key >= s - W1) && (key <= s + W1) && (key >= 0) && (key < S_LEN);
            float p = valid ? __expf(accS[n][r] * 0.125f) : 0.f;
            accS[n][r] = p;
            l4[r] += p;
        }
    }
    #pragma unroll
    for (int m = 1; m <= 8; m <<= 1)
        #pragma unroll
        for (int r = 0; r < 4; ++r) l4[r] += __shfl_xor(l4[r], m, 64);

    // ---- P -> LDS in A-layout ----
    #pragma unroll
    for (int n = 0; n < 6; ++n)
        #pragma unroll
        for (int r = 0; r < 4; ++r)
            pl[w][q * 4 + r][n * 16 + cl] = f2bf(accS[n][r]);

    // ---- O = P . V (MFMA over 3 key-chunks of 32) ----
    f32x4 accO[4];
    #pragma unroll
    for (int n = 0; n < 4; ++n) accO[n] = fzero;
    bf16x8 ap[3];
    #pragma unroll
    for (int ks = 0; ks < 3; ++ks)
        ap[ks] = *(const bf16x8*)&pl[w][cl][ks * 32 + q * 8];
    #pragma unroll
    for (int n = 0; n < 4; ++n)
        #pragma unroll
        for (int ks = 0; ks < 3; ++ks) {
            bf16x8 bv8 = *(const bf16x8*)&vt[n * 16 + cl][ks * 32 + q * 8];
            accO[n] = __builtin_amdgcn_mfma_f32_16x16x32_bf16(ap[ks], bv8, accO[n], 0, 0, 0);
        }

    // ---- normalize rows, pool over the wave's 16 queries, LDS reduce ----
    float rcp4[4];
    #pragma unroll
    for (int r = 0; r < 4; ++r) rcp4[r] = 1.0f / l4[r];
    #pragma unroll
    for (int n = 0; n < 4; ++n) {
        float pp = 0.f;
        #pragma unroll
        for (int r = 0; r < 4; ++r) pp += accO[n][r] * rcp4[r];
        pp += __shfl_xor(pp, 16, 64);
        pp += __shfl_xor(pp, 32, 64);
        if (q == 0) pr[w][n * 16 + cl] = pp;
    }
    __syncthreads();
    if (t < 64) {
        long pb = (((long)(b * NH + h) * 32) + blockIdx.x) * 64 + t;
        partial[pb] = pr[0][t] + pr[1][t];
    }
}

// ---------------------------------------------------------------------------
// Kernel 4: out = relu((sum_sblk partial)/S @ Wfc + bfc) -> f32.
// NEW: 48 blocks = (batch, col-tile of 32) — halves each block's serial
// Wfc read (196 -> 98 KB); this kernel is parallelism-starved at 24 blocks.
// ---------------------------------------------------------------------------
__global__ __launch_bounds__(256) void fc_relu_f(
    const float* __restrict__ partial, const float* __restrict__ Wfc,
    const float* __restrict__ bfc, float* __restrict__ out) {
    __shared__ float red[8][32];
    __shared__ float ps[768];
    const int t = threadIdx.x;
    const int nb = blockIdx.x % 24;     // col tile (32 wide)
    const int bb = blockIdx.x / 24;     // batch

    for (int d = t; d < DM; d += 256) {
        const float* pp = partial + ((long)(bb * NH + (d >> 6)) * 32) * 64 + (d & 63);
        float s = 0.f;
        #pragma unroll
        for (int sb = 0; sb < 32; ++sb) s += pp[sb * 64];
        ps[d] = s;
    }
    __syncthreads();

    const int nn = t & 31;
    const int dg = t >> 5;              // 0..7, 96 d each
    const int n = nb * 32 + nn;
    float s = 0.f;
    for (int d = dg * 96; d < dg * 96 + 96; ++d)
        s += ps[d] * Wfc[(long)d * DM + n];
    red[dg][nn] = s;
    __syncthreads();
    if (t < 32) {
        float sum = red[0][t] + red[1][t] + red[2][t] + red[3][t]
                  + red[4][t] + red[5][t] + red[6][t] + red[7][t];
        sum = sum * (1.0f / (float)S_LEN) + bfc[nb * 32 + t];
        sum = sum > 0.f ? sum : 0.f;
        out[bb * DM + nb * 32 + t] = sum;
    }
}

// ---------------------------------------------------------------------------
extern "C" void kernel_launch(void* const* d_in, const int* in_sizes, int n_in,
                              void* d_out, int out_size, void* d_ws, size_t ws_size,
                              hipStream_t stream) {
    const float* X   = (const float*)d_in[0];
    const float* Wq  = (const float*)d_in[1];
    const float* bq  = (const float*)d_in[2];
    const float* Wk  = (const float*)d_in[3];
    const float* bk  = (const float*)d_in[4];
    const float* Wv  = (const float*)d_in[5];
    const float* bv  = (const float*)d_in[6];
    const float* Wfc = (const float*)d_in[7];
    const float* bfc = (const float*)d_in[8];

    char* ws = (char*)d_ws;
    const size_t SZ_XB = (size_t)M_TOT * DM * 2;              // 3,145,728
    const size_t SZ_WB = (size_t)NQKV * DM * 2;               // 3,538,944
    u16* Xb = (u16*)(ws);
    u16* Wt = (u16*)(ws + SZ_XB);
    u16* Qp = (u16*)(ws + SZ_XB + SZ_WB);
    u16* Kp = (u16*)(ws + 2 * SZ_XB + SZ_WB);
    u16* Vt = (u16*)(ws + 3 * SZ_XB + SZ_WB);
    float* partial = (float*)(ws + 4 * SZ_XB + SZ_WB);        // [2][12][32][64] f32

    prep<<<1200, 256, 0, stream>>>(X, Wq, Wk, Wv, Xb, Wt);

    qkv_gemm_mfma<<<768, 256, 0, stream>>>(
        Xb, Wt, bq, bk, bv, Qp, Kp, Vt);

    attn_pool_mfma<<<dim3(32, NH, BATCH), 128, 0, stream>>>(
        Qp, Kp, Vt, partial);

    fc_relu_f<<<48, 256, 0, stream>>>(partial, Wfc, bfc, (float*)d_out);
}

// Round 6
// 115.246 us; speedup vs baseline: 4.4053x; 1.0027x over previous
//
#include <hip/hip_runtime.h>
#include <hip/hip_bf16.h>
#include <stdint.h>

#define S_LEN 1024
#define BATCH 2
#define DM    768
#define NH    12
#define HD    64
#define W1    32
#define WIN   65
#define NQKV  2304
#define M_TOT 2048

typedef unsigned short u16;
typedef __attribute__((ext_vector_type(4))) float f4;
typedef __attribute__((ext_vector_type(4))) unsigned short us4;
typedef __attribute__((ext_vector_type(8))) unsigned short ushort8;
typedef __attribute__((ext_vector_type(8))) __bf16 bf16x8;
typedef __attribute__((ext_vector_type(4))) float f32x4;

__device__ inline u16 f2bf(float x) {
    union { float f; unsigned u; } z;
    z.f = x;
    unsigned r = z.u + 0x7FFF + ((z.u >> 16) & 1);   // RNE
    return (u16)(r >> 16);
}

// async global->LDS, 16B per lane. LDS dest is wave-uniform base + lane*16.
__device__ __forceinline__ void g2l16(const u16* g, u16* l) {
    __builtin_amdgcn_global_load_lds(
        (const __attribute__((address_space(1))) unsigned int*)g,
        (__attribute__((address_space(3))) unsigned int*)l, 16, 0, 0);
}

// ---------------------------------------------------------------------------
// Kernel 1: prep. Blocks [0,768): X f32 -> Xb bf16. Blocks [768,1200):
// transpose+concat weights -> Wt bf16 [n][k].
// ---------------------------------------------------------------------------
__global__ __launch_bounds__(256) void prep(
    const float* __restrict__ X,
    const float* __restrict__ Wq, const float* __restrict__ Wk,
    const float* __restrict__ Wv,
    u16* __restrict__ Xb, u16* __restrict__ Wt) {
    __shared__ float tile[64][69];
    const int t = threadIdx.x;
    const int bid = blockIdx.x;

    if (bid < 768) {
        const long base = (long)bid * 2048 + t * 8;
        f4 a = *(const f4*)&X[base];
        f4 b = *(const f4*)&X[base + 4];
        float v[8] = {a.x, a.y, a.z, a.w, b.x, b.y, b.z, b.w};
        ushort8 h;
        #pragma unroll
        for (int j = 0; j < 8; ++j) h[j] = f2bf(v[j]);
        *(ushort8*)&Xb[base] = h;
    } else {
        const int tw = bid - 768;           // 0..431
        const int n0 = (tw % 36) * 64;      // 0..2240
        const int k0 = (tw / 36) * 64;      // 0..704
        const int sel = n0 / DM;
        const int nl0 = n0 % DM;
        const float* W = (sel == 0) ? Wq : ((sel == 1) ? Wk : Wv);
        const int r = t >> 3;               // 0..31
        const int cg8 = t & 7;              // 0..7

        #pragma unroll
        for (int p = 0; p < 2; ++p) {
            int rr = r + p * 32;            // source row (k)
            long gb = (long)(k0 + rr) * DM + nl0 + cg8 * 8;
            *(f4*)&tile[rr][cg8 * 8]     = *(const f4*)&W[gb];
            *(f4*)&tile[rr][cg8 * 8 + 4] = *(const f4*)&W[gb + 4];
        }
        __syncthreads();
        #pragma unroll
        for (int p = 0; p < 2; ++p) {
            int rn = r + p * 32;            // output row (n)
            ushort8 h;
            #pragma unroll
            for (int jj = 0; jj < 8; ++jj)
                h[jj] = f2bf(tile[cg8 * 8 + jj][rn]);
            *(ushort8*)&Wt[(long)(n0 + rn) * DM + k0 + cg8 * 8] = h;
        }
    }
}

// ---------------------------------------------------------------------------
// Kernel 2: fused QKV GEMM, plain bf16 MFMA (round-5 verified).
// 64x96 tile (MxN), 32x24 = 768 blocks = exactly 3 blocks/CU. 40 KB LDS
// dbuf; 2-phase gload_lds + source-side XOR swizzle.
// ---------------------------------------------------------------------------
__global__ __launch_bounds__(256) void qkv_gemm_mfma(
    const u16* __restrict__ Xb, const u16* __restrict__ Wt,
    const float* __restrict__ bq, const float* __restrict__ bk,
    const float* __restrict__ bv,
    u16* __restrict__ Q, u16* __restrict__ K, u16* __restrict__ Vt) {
    __shared__ u16 As[2][64 * 64];     // 8 KB per buffer
    __shared__ u16 Bs[2][96 * 64];     // 12 KB per buffer

    const int bid = blockIdx.x;         // 0..767
    const int xcd = bid & 7;            // presumed XCD (RR dispatch)
    const int local = bid >> 3;         // 0..95 within XCD
    const int nt = local % 24;          // 0..23
    const int mt = (xcd << 2) + (local / 24);   // 0..31
    const int m0 = mt * 64;
    const int n0 = nt * 96;
    const int t = threadIdx.x;
    const int lane = t & 63;
    const int w = t >> 6;
    const int wm = w * 16;              // wave's M offset (16-row strip)
    const int lrow = lane & 15;
    const int lq = lane >> 4;

    // pre-swizzled global sources (XOR swizzle on source, LDS lane-linear)
    const u16* gA[2];
    const u16* gB[3];
    #pragma unroll
    for (int p = 0; p < 2; ++p) {
        int slot = p * 256 + t;         // 0..511 -> 64 rows x 8 chunks
        int row = slot >> 3;
        int skc = (slot & 7) ^ (row & 7);
        gA[p] = Xb + (long)(m0 + row) * DM + skc * 8;
    }
    #pragma unroll
    for (int p = 0; p < 3; ++p) {
        int slot = p * 256 + t;         // 0..767 -> 96 rows x 8 chunks
        int row = slot >> 3;
        int skc = (slot & 7) ^ (row & 7);
        gB[p] = Wt + (long)(n0 + row) * DM + skc * 8;
    }

#define STAGE(buf)                                                          \
    do {                                                                    \
        _Pragma("unroll")                                                   \
        for (int p = 0; p < 2; ++p)                                         \
            g2l16(gA[p], &As[buf][(p * 256 + w * 64) * 8]);                 \
        _Pragma("unroll")                                                   \
        for (int p = 0; p < 3; ++p)                                         \
            g2l16(gB[p], &Bs[buf][(p * 256 + w * 64) * 8]);                 \
        _Pragma("unroll")                                                   \
        for (int p = 0; p < 2; ++p) gA[p] += 64;                            \
        _Pragma("unroll")                                                   \
        for (int p = 0; p < 3; ++p) gB[p] += 64;                            \
    } while (0)

    const f32x4 fzero = {0.f, 0.f, 0.f, 0.f};
    f32x4 acc[6];
    #pragma unroll
    for (int j = 0; j < 6; ++j) acc[j] = fzero;

    STAGE(0);
    __syncthreads();    // drains vmcnt(0): tile 0 resident

    #pragma unroll
    for (int ks = 0; ks < 12; ++ks) {
        const int cb = ks & 1;
        if (ks < 11) STAGE(cb ^ 1);     // async prefetch overlaps compute
        #pragma unroll
        for (int kh = 0; kh < 2; ++kh) {
            const int c = kh * 4 + lq;
            const int ar = wm + lrow;   // 0..63
            bf16x8 ah = *(const bf16x8*)&As[cb][(ar * 8 + (c ^ (ar & 7))) * 8];
            bf16x8 bh[6];
            #pragma unroll
            for (int j = 0; j < 6; ++j) {
                int br = j * 16 + lrow; // 0..95
                bh[j] = *(const bf16x8*)&Bs[cb][(br * 8 + (c ^ (br & 7))) * 8];
            }
            #pragma unroll
            for (int j = 0; j < 6; ++j)
                acc[j] = __builtin_amdgcn_mfma_f32_16x16x32_bf16(
                    ah, bh[j], acc[j], 0, 0, 0);
        }
        if (ks < 11) __syncthreads();
    }
#undef STAGE

    const int region = n0 / DM;     // 0=Q, 1=K, 2=V
    const int nc0 = n0 % DM;        // 0,96,...,672
    const float* bias = (region == 0) ? bq : ((region == 1) ? bk : bv);
    const int row = m0 + wm + lq * 4;

    if (region < 2) {
        u16* Out = (region == 0) ? Q : K;
        #pragma unroll
        for (int j = 0; j < 6; ++j) {
            int col = nc0 + j * 16 + lrow;
            float bval = bias[col];
            #pragma unroll
            for (int r = 0; r < 4; ++r)
                Out[(long)(row + r) * DM + col] = f2bf(acc[j][r] + bval);
        }
    } else {
        // V: write transposed bf16 Vt[b][h][dloc][s]
        const int b = row >> 10, sl = row & 1023;
        #pragma unroll
        for (int j = 0; j < 6; ++j) {
            int c = nc0 + j * 16 + lrow;    // global V column 0..767
            int h = c >> 6, dloc = c & 63;  // head / in-head dim
            float bval = bias[c];
            us4 pk;
            #pragma unroll
            for (int r = 0; r < 4; ++r) pk[r] = f2bf(acc[j][r] + bval);
            *(us4*)&Vt[(((long)(b * NH + h) * 64 + dloc) << 10) + sl] = pk;
        }
    }
}

// ---------------------------------------------------------------------------
// Kernel 3: MFMA flash attention + pooled partial.
// NEW (T14 issue-early reordering; math/order bitwise identical):
//  1. Q + all 12 K fragment loads issued FIRST into VGPRs;
//  2. V^T window staged to LDS (its loads pipeline behind K/Q's);
//  3. QK^T MFMA + softmax + P->LDS run BEFORE the barrier (none of them
//     read other threads' LDS; P round-trips within the same wave);
//  4. single __syncthreads() just before PV — V's LDS writes get the whole
//     QK+softmax phase to drain, so the barrier stall ~0.
// Round-4 evidence says this kernel is latency-bound (direct-global V cost
// +11 us), so hiding the two exposed-latency segments is the lever.
// ---------------------------------------------------------------------------
__global__ __launch_bounds__(128) void attn_pool_mfma(
    const u16* __restrict__ Q, const u16* __restrict__ K,
    const u16* __restrict__ Vt, float* __restrict__ partial) {
    __shared__ u16 vt[64][104];        // V^T window: [d][key 96 + pad 8]
    __shared__ u16 pl[2][16][104];     // per-wave P: [wave][query row][key]
    __shared__ float pr[2][64];        // per-wave pooled partials
    const int b = blockIdx.z, h = blockIdx.y;
    const int s0 = blockIdx.x * 32;
    const int t = threadIdx.x;
    const int k0 = s0 - 32;

    const int w = t >> 6, lane = t & 63;
    const int cl = lane & 15, q = lane >> 4;

    // ---- 1. issue Q + K fragment loads first (hidden under V staging) ----
    const long qrow = (long)(b * S_LEN + s0 + w * 16 + cl);
    bf16x8 aq[2];
    #pragma unroll
    for (int ks = 0; ks < 2; ++ks)
        aq[ks] = *(const bf16x8*)&Q[qrow * DM + h * HD + ks * 32 + q * 8];
    bf16x8 bk[6][2];
    #pragma unroll
    for (int n = 0; n < 6; ++n) {
        int key = k0 + n * 16 + cl;
        int kcl = key < 0 ? 0 : (key > S_LEN - 1 ? S_LEN - 1 : key);
        long ka = (long)(b * S_LEN + kcl) * DM + h * HD;
        #pragma unroll
        for (int ks = 0; ks < 2; ++ks)
            bk[n][ks] = *(const bf16x8*)&K[ka + ks * 32 + q * 8];
    }

    // ---- 2. stage V^T window: 64 d x 96 keys ----
    const u16* vtg = Vt + ((size_t)(b * NH + h) * 64) * 1024;
    #pragma unroll
    for (int it = 0; it < 6; ++it) {
        int slot = it * 128 + t;        // 0..767
        int d = slot / 12, kc = slot % 12;
        int kbase = k0 + kc * 8;
        if (kbase >= 0 && kbase + 7 < S_LEN) {
            *(ushort8*)&vt[d][kc * 8] = *(const ushort8*)&vtg[d * 1024 + kbase];
        } else {
            #pragma unroll
            for (int j = 0; j < 8; ++j) {
                int kk = kbase + j;
                int kcl = kk < 0 ? 0 : (kk > S_LEN - 1 ? S_LEN - 1 : kk);
                vt[d][kc * 8 + j] = vtg[d * 1024 + kcl];
            }
        }
    }

    // ---- 3a. scores: S = Q . K^T (operands already in regs) ----
    const f32x4 fzero = {0.f, 0.f, 0.f, 0.f};
    f32x4 accS[6];
    #pragma unroll
    for (int n = 0; n < 6; ++n) accS[n] = fzero;
    #pragma unroll
    for (int n = 0; n < 6; ++n)
        #pragma unroll
        for (int ks = 0; ks < 2; ++ks)
            accS[n] = __builtin_amdgcn_mfma_f32_16x16x32_bf16(
                aq[ks], bk[n][ks], accS[n], 0, 0, 0);

    // ---- 3b. softmax (unnormalized) in C-layout: col=cl(key), row=q*4+r --
    float l4[4] = {0.f, 0.f, 0.f, 0.f};
    #pragma unroll
    for (int n = 0; n < 6; ++n) {
        int key = k0 + n * 16 + cl;
        #pragma unroll
        for (int r = 0; r < 4; ++r) {
            int s = s0 + w * 16 + q * 4 + r;
            bool valid = (key >= s - W1) && (key <= s + W1) && (key >= 0) && (key < S_LEN);
            float p = valid ? __expf(accS[n][r] * 0.125f) : 0.f;
            accS[n][r] = p;
            l4[r] += p;
        }
    }
    #pragma unroll
    for (int m = 1; m <= 8; m <<= 1)
        #pragma unroll
        for (int r = 0; r < 4; ++r) l4[r] += __shfl_xor(l4[r], m, 64);

    // ---- 3c. P -> LDS in A-layout (same-wave round trip) ----
    #pragma unroll
    for (int n = 0; n < 6; ++n)
        #pragma unroll
        for (int r = 0; r < 4; ++r)
            pl[w][q * 4 + r][n * 16 + cl] = f2bf(accS[n][r]);

    // ---- 4. barrier: vt writes have had the whole QK+softmax phase ----
    __syncthreads();

    // ---- 5. O = P . V (MFMA over 3 key-chunks of 32) ----
    f32x4 accO[4];
    #pragma unroll
    for (int n = 0; n < 4; ++n) accO[n] = fzero;
    bf16x8 ap[3];
    #pragma unroll
    for (int ks = 0; ks < 3; ++ks)
        ap[ks] = *(const bf16x8*)&pl[w][cl][ks * 32 + q * 8];
    #pragma unroll
    for (int n = 0; n < 4; ++n)
        #pragma unroll
        for (int ks = 0; ks < 3; ++ks) {
            bf16x8 bv8 = *(const bf16x8*)&vt[n * 16 + cl][ks * 32 + q * 8];
            accO[n] = __builtin_amdgcn_mfma_f32_16x16x32_bf16(ap[ks], bv8, accO[n], 0, 0, 0);
        }

    // ---- 6. normalize rows, pool over the wave's 16 queries, LDS reduce --
    float rcp4[4];
    #pragma unroll
    for (int r = 0; r < 4; ++r) rcp4[r] = 1.0f / l4[r];
    #pragma unroll
    for (int n = 0; n < 4; ++n) {
        float pp = 0.f;
        #pragma unroll
        for (int r = 0; r < 4; ++r) pp += accO[n][r] * rcp4[r];
        pp += __shfl_xor(pp, 16, 64);
        pp += __shfl_xor(pp, 32, 64);
        if (q == 0) pr[w][n * 16 + cl] = pp;
    }
    __syncthreads();
    if (t < 64) {
        long pb = (((long)(b * NH + h) * 32) + blockIdx.x) * 64 + t;
        partial[pb] = pr[0][t] + pr[1][t];
    }
}

// ---------------------------------------------------------------------------
// Kernel 4: out = relu((sum_sblk partial)/S @ Wfc + bfc) -> f32.
// 48 blocks = (batch, col-tile of 32).
// ---------------------------------------------------------------------------
__global__ __launch_bounds__(256) void fc_relu_f(
    const float* __restrict__ partial, const float* __restrict__ Wfc,
    const float* __restrict__ bfc, float* __restrict__ out) {
    __shared__ float red[8][32];
    __shared__ float ps[768];
    const int t = threadIdx.x;
    const int nb = blockIdx.x % 24;     // col tile (32 wide)
    const int bb = blockIdx.x / 24;     // batch

    for (int d = t; d < DM; d += 256) {
        const float* pp = partial + ((long)(bb * NH + (d >> 6)) * 32) * 64 + (d & 63);
        float s = 0.f;
        #pragma unroll
        for (int sb = 0; sb < 32; ++sb) s += pp[sb * 64];
        ps[d] = s;
    }
    __syncthreads();

    const int nn = t & 31;
    const int dg = t >> 5;              // 0..7, 96 d each
    const int n = nb * 32 + nn;
    float s = 0.f;
    for (int d = dg * 96; d < dg * 96 + 96; ++d)
        s += ps[d] * Wfc[(long)d * DM + n];
    red[dg][nn] = s;
    __syncthreads();
    if (t < 32) {
        float sum = red[0][t] + red[1][t] + red[2][t] + red[3][t]
                  + red[4][t] + red[5][t] + red[6][t] + red[7][t];
        sum = sum * (1.0f / (float)S_LEN) + bfc[nb * 32 + t];
        sum = sum > 0.f ? sum : 0.f;
        out[bb * DM + nb * 32 + t] = sum;
    }
}

// ---------------------------------------------------------------------------
extern "C" void kernel_launch(void* const* d_in, const int* in_sizes, int n_in,
                              void* d_out, int out_size, void* d_ws, size_t ws_size,
                              hipStream_t stream) {
    const float* X   = (const float*)d_in[0];
    const float* Wq  = (const float*)d_in[1];
    const float* bq  = (const float*)d_in[2];
    const float* Wk  = (const float*)d_in[3];
    const float* bk  = (const float*)d_in[4];
    const float* Wv  = (const float*)d_in[5];
    const float* bv  = (const float*)d_in[6];
    const float* Wfc = (const float*)d_in[7];
    const float* bfc = (const float*)d_in[8];

    char* ws = (char*)d_ws;
    const size_t SZ_XB = (size_t)M_TOT * DM * 2;              // 3,145,728
    const size_t SZ_WB = (size_t)NQKV * DM * 2;               // 3,538,944
    u16* Xb = (u16*)(ws);
    u16* Wt = (u16*)(ws + SZ_XB);
    u16* Qp = (u16*)(ws + SZ_XB + SZ_WB);
    u16* Kp = (u16*)(ws + 2 * SZ_XB + SZ_WB);
    u16* Vt = (u16*)(ws + 3 * SZ_XB + SZ_WB);
    float* partial = (float*)(ws + 4 * SZ_XB + SZ_WB);        // [2][12][32][64] f32

    prep<<<1200, 256, 0, stream>>>(X, Wq, Wk, Wv, Xb, Wt);

    qkv_gemm_mfma<<<768, 256, 0, stream>>>(
        Xb, Wt, bq, bk, bv, Qp, Kp, Vt);

    attn_pool_mfma<<<dim3(32, NH, BATCH), 128, 0, stream>>>(
        Qp, Kp, Vt, partial);

    fc_relu_f<<<48, 256, 0, stream>>>(partial, Wfc, bfc, (float*)d_out);
}

// Round 8
// 114.589 us; speedup vs baseline: 4.4306x; 1.0057x over previous
//
#include <hip/hip_runtime.h>
#include <hip/hip_bf16.h>
#include <stdint.h>

#define S_LEN 1024
#define BATCH 2
#define DM    768
#define NH    12
#define HD    64
#define W1    32
#define WIN   65
#define NQKV  2304
#define M_TOT 2048

typedef unsigned short u16;
typedef __attribute__((ext_vector_type(4))) float f4;
typedef __attribute__((ext_vector_type(4))) unsigned short us4;
typedef __attribute__((ext_vector_type(8))) unsigned short ushort8;
typedef __attribute__((ext_vector_type(8))) __bf16 bf16x8;
typedef __attribute__((ext_vector_type(4))) float f32x4;

__device__ inline u16 f2bf(float x) {
    union { float f; unsigned u; } z;
    z.f = x;
    unsigned r = z.u + 0x7FFF + ((z.u >> 16) & 1);   // RNE
    return (u16)(r >> 16);
}

// async global->LDS, 16B per lane. LDS dest is wave-uniform base + lane*16.
__device__ __forceinline__ void g2l16(const u16* g, u16* l) {
    __builtin_amdgcn_global_load_lds(
        (const __attribute__((address_space(1))) unsigned int*)g,
        (__attribute__((address_space(3))) unsigned int*)l, 16, 0, 0);
}

// ---------------------------------------------------------------------------
// Kernel 1: prep. Blocks [0,768): X f32 -> Xb bf16. Blocks [768,1200):
// transpose+concat weights -> Wt bf16 [n][k].
// ---------------------------------------------------------------------------
__global__ __launch_bounds__(256) void prep(
    const float* __restrict__ X,
    const float* __restrict__ Wq, const float* __restrict__ Wk,
    const float* __restrict__ Wv,
    u16* __restrict__ Xb, u16* __restrict__ Wt) {
    __shared__ float tile[64][69];
    const int t = threadIdx.x;
    const int bid = blockIdx.x;

    if (bid < 768) {
        const long base = (long)bid * 2048 + t * 8;
        f4 a = *(const f4*)&X[base];
        f4 b = *(const f4*)&X[base + 4];
        float v[8] = {a.x, a.y, a.z, a.w, b.x, b.y, b.z, b.w};
        ushort8 h;
        #pragma unroll
        for (int j = 0; j < 8; ++j) h[j] = f2bf(v[j]);
        *(ushort8*)&Xb[base] = h;
    } else {
        const int tw = bid - 768;           // 0..431
        const int n0 = (tw % 36) * 64;      // 0..2240
        const int k0 = (tw / 36) * 64;      // 0..704
        const int sel = n0 / DM;
        const int nl0 = n0 % DM;
        const float* W = (sel == 0) ? Wq : ((sel == 1) ? Wk : Wv);
        const int r = t >> 3;               // 0..31
        const int cg8 = t & 7;              // 0..7

        #pragma unroll
        for (int p = 0; p < 2; ++p) {
            int rr = r + p * 32;            // source row (k)
            long gb = (long)(k0 + rr) * DM + nl0 + cg8 * 8;
            *(f4*)&tile[rr][cg8 * 8]     = *(const f4*)&W[gb];
            *(f4*)&tile[rr][cg8 * 8 + 4] = *(const f4*)&W[gb + 4];
        }
        __syncthreads();
        #pragma unroll
        for (int p = 0; p < 2; ++p) {
            int rn = r + p * 32;            // output row (n)
            ushort8 h;
            #pragma unroll
            for (int jj = 0; jj < 8; ++jj)
                h[jj] = f2bf(tile[cg8 * 8 + jj][rn]);
            *(ushort8*)&Wt[(long)(n0 + rn) * DM + k0 + cg8 * 8] = h;
        }
    }
}

// ---------------------------------------------------------------------------
// Kernel 2: fused QKV GEMM, plain bf16 MFMA (round-5/6 verified).
// 64x96 tile (MxN), 32x24 = 768 blocks = exactly 3 blocks/CU. 40 KB LDS
// dbuf; 2-phase gload_lds + source-side XOR swizzle. Standard __syncthreads
// only — raw s_barrier/counted-vmcnt variants (R7) and grid-sync fusion (R2)
// both failed the platform; do not reintroduce.
// ---------------------------------------------------------------------------
__global__ __launch_bounds__(256) void qkv_gemm_mfma(
    const u16* __restrict__ Xb, const u16* __restrict__ Wt,
    const float* __restrict__ bq, const float* __restrict__ bk,
    const float* __restrict__ bv,
    u16* __restrict__ Q, u16* __restrict__ K, u16* __restrict__ Vt) {
    __shared__ u16 As[2][64 * 64];     // 8 KB per buffer
    __shared__ u16 Bs[2][96 * 64];     // 12 KB per buffer

    const int bid = blockIdx.x;         // 0..767
    const int xcd = bid & 7;            // presumed XCD (RR dispatch)
    const int local = bid >> 3;         // 0..95 within XCD
    const int nt = local % 24;          // 0..23
    const int mt = (xcd << 2) + (local / 24);   // 0..31
    const int m0 = mt * 64;
    const int n0 = nt * 96;
    const int t = threadIdx.x;
    const int lane = t & 63;
    const int w = t >> 6;
    const int wm = w * 16;              // wave's M offset (16-row strip)
    const int lrow = lane & 15;
    const int lq = lane >> 4;

    // pre-swizzled global sources (XOR swizzle on source, LDS lane-linear)
    const u16* gA[2];
    const u16* gB[3];
    #pragma unroll
    for (int p = 0; p < 2; ++p) {
        int slot = p * 256 + t;         // 0..511 -> 64 rows x 8 chunks
        int row = slot >> 3;
        int skc = (slot & 7) ^ (row & 7);
        gA[p] = Xb + (long)(m0 + row) * DM + skc * 8;
    }
    #pragma unroll
    for (int p = 0; p < 3; ++p) {
        int slot = p * 256 + t;         // 0..767 -> 96 rows x 8 chunks
        int row = slot >> 3;
        int skc = (slot & 7) ^ (row & 7);
        gB[p] = Wt + (long)(n0 + row) * DM + skc * 8;
    }

#define STAGE(buf)                                                          \
    do {                                                                    \
        _Pragma("unroll")                                                   \
        for (int p = 0; p < 2; ++p)                                         \
            g2l16(gA[p], &As[buf][(p * 256 + w * 64) * 8]);                 \
        _Pragma("unroll")                                                   \
        for (int p = 0; p < 3; ++p)                                         \
            g2l16(gB[p], &Bs[buf][(p * 256 + w * 64) * 8]);                 \
        _Pragma("unroll")                                                   \
        for (int p = 0; p < 2; ++p) gA[p] += 64;                            \
        _Pragma("unroll")                                                   \
        for (int p = 0; p < 3; ++p) gB[p] += 64;                            \
    } while (0)

    const f32x4 fzero = {0.f, 0.f, 0.f, 0.f};
    f32x4 acc[6];
    #pragma unroll
    for (int j = 0; j < 6; ++j) acc[j] = fzero;

    STAGE(0);
    __syncthreads();    // drains vmcnt(0): tile 0 resident

    #pragma unroll
    for (int ks = 0; ks < 12; ++ks) {
        const int cb = ks & 1;
        if (ks < 11) STAGE(cb ^ 1);     // async prefetch overlaps compute
        #pragma unroll
        for (int kh = 0; kh < 2; ++kh) {
            const int c = kh * 4 + lq;
            const int ar = wm + lrow;   // 0..63
            bf16x8 ah = *(const bf16x8*)&As[cb][(ar * 8 + (c ^ (ar & 7))) * 8];
            bf16x8 bh[6];
            #pragma unroll
            for (int j = 0; j < 6; ++j) {
                int br = j * 16 + lrow; // 0..95
                bh[j] = *(const bf16x8*)&Bs[cb][(br * 8 + (c ^ (br & 7))) * 8];
            }
            #pragma unroll
            for (int j = 0; j < 6; ++j)
                acc[j] = __builtin_amdgcn_mfma_f32_16x16x32_bf16(
                    ah, bh[j], acc[j], 0, 0, 0);
        }
        if (ks < 11) __syncthreads();
    }
#undef STAGE

    const int region = n0 / DM;     // 0=Q, 1=K, 2=V
    const int nc0 = n0 % DM;        // 0,96,...,672
    const float* bias = (region == 0) ? bq : ((region == 1) ? bk : bv);
    const int row = m0 + wm + lq * 4;

    if (region < 2) {
        u16* Out = (region == 0) ? Q : K;
        #pragma unroll
        for (int j = 0; j < 6; ++j) {
            int col = nc0 + j * 16 + lrow;
            float bval = bias[col];
            #pragma unroll
            for (int r = 0; r < 4; ++r)
                Out[(long)(row + r) * DM + col] = f2bf(acc[j][r] + bval);
        }
    } else {
        // V: write transposed bf16 Vt[b][h][dloc][s]
        const int b = row >> 10, sl = row & 1023;
        #pragma unroll
        for (int j = 0; j < 6; ++j) {
            int c = nc0 + j * 16 + lrow;    // global V column 0..767
            int h = c >> 6, dloc = c & 63;  // head / in-head dim
            float bval = bias[c];
            us4 pk;
            #pragma unroll
            for (int r = 0; r < 4; ++r) pk[r] = f2bf(acc[j][r] + bval);
            *(us4*)&Vt[(((long)(b * NH + h) * 64 + dloc) << 10) + sl] = pk;
        }
    }
}

// ---------------------------------------------------------------------------
// Kernel 3: MFMA flash attention + pooled partial (round-6 verified:
// T14 issue-early Q/K loads, V^T staged in LDS, single pre-PV barrier).
// ---------------------------------------------------------------------------
__global__ __launch_bounds__(128) void attn_pool_mfma(
    const u16* __restrict__ Q, const u16* __restrict__ K,
    const u16* __restrict__ Vt, float* __restrict__ partial) {
    __shared__ u16 vt[64][104];        // V^T window: [d][key 96 + pad 8]
    __shared__ u16 pl[2][16][104];     // per-wave P: [wave][query row][key]
    __shared__ float pr[2][64];        // per-wave pooled partials
    const int b = blockIdx.z, h = blockIdx.y;
    const int s0 = blockIdx.x * 32;
    const int t = threadIdx.x;
    const int k0 = s0 - 32;

    const int w = t >> 6, lane = t & 63;
    const int cl = lane & 15, q = lane >> 4;

    // ---- 1. issue Q + K fragment loads first (hidden under V staging) ----
    const long qrow = (long)(b * S_LEN + s0 + w * 16 + cl);
    bf16x8 aq[2];
    #pragma unroll
    for (int ks = 0; ks < 2; ++ks)
        aq[ks] = *(const bf16x8*)&Q[qrow * DM + h * HD + ks * 32 + q * 8];
    bf16x8 bk[6][2];
    #pragma unroll
    for (int n = 0; n < 6; ++n) {
        int key = k0 + n * 16 + cl;
        int kcl = key < 0 ? 0 : (key > S_LEN - 1 ? S_LEN - 1 : key);
        long ka = (long)(b * S_LEN + kcl) * DM + h * HD;
        #pragma unroll
        for (int ks = 0; ks < 2; ++ks)
            bk[n][ks] = *(const bf16x8*)&K[ka + ks * 32 + q * 8];
    }

    // ---- 2. stage V^T window: 64 d x 96 keys ----
    const u16* vtg = Vt + ((size_t)(b * NH + h) * 64) * 1024;
    #pragma unroll
    for (int it = 0; it < 6; ++it) {
        int slot = it * 128 + t;        // 0..767
        int d = slot / 12, kc = slot % 12;
        int kbase = k0 + kc * 8;
        if (kbase >= 0 && kbase + 7 < S_LEN) {
            *(ushort8*)&vt[d][kc * 8] = *(const ushort8*)&vtg[d * 1024 + kbase];
        } else {
            #pragma unroll
            for (int j = 0; j < 8; ++j) {
                int kk = kbase + j;
                int kcl = kk < 0 ? 0 : (kk > S_LEN - 1 ? S_LEN - 1 : kk);
                vt[d][kc * 8 + j] = vtg[d * 1024 + kcl];
            }
        }
    }

    // ---- 3a. scores: S = Q . K^T (operands already in regs) ----
    const f32x4 fzero = {0.f, 0.f, 0.f, 0.f};
    f32x4 accS[6];
    #pragma unroll
    for (int n = 0; n < 6; ++n) accS[n] = fzero;
    #pragma unroll
    for (int n = 0; n < 6; ++n)
        #pragma unroll
        for (int ks = 0; ks < 2; ++ks)
            accS[n] = __builtin_amdgcn_mfma_f32_16x16x32_bf16(
                aq[ks], bk[n][ks], accS[n], 0, 0, 0);

    // ---- 3b. softmax (unnormalized) in C-layout: col=cl(key), row=q*4+r --
    float l4[4] = {0.f, 0.f, 0.f, 0.f};
    #pragma unroll
    for (int n = 0; n < 6; ++n) {
        int key = k0 + n * 16 + cl;
        #pragma unroll
        for (int r = 0; r < 4; ++r) {
            int s = s0 + w * 16 + q * 4 + r;
            bool valid = (key >= s - W1) && (key <= s + W1) && (key >= 0) && (key < S_LEN);
            float p = valid ? __expf(accS[n][r] * 0.125f) : 0.f;
            accS[n][r] = p;
            l4[r] += p;
        }
    }
    #pragma unroll
    for (int m = 1; m <= 8; m <<= 1)
        #pragma unroll
        for (int r = 0; r < 4; ++r) l4[r] += __shfl_xor(l4[r], m, 64);

    // ---- 3c. P -> LDS in A-layout (same-wave round trip) ----
    #pragma unroll
    for (int n = 0; n < 6; ++n)
        #pragma unroll
        for (int r = 0; r < 4; ++r)
            pl[w][q * 4 + r][n * 16 + cl] = f2bf(accS[n][r]);

    // ---- 4. barrier: vt writes have had the whole QK+softmax phase ----
    __syncthreads();

    // ---- 5. O = P . V (MFMA over 3 key-chunks of 32) ----
    f32x4 accO[4];
    #pragma unroll
    for (int n = 0; n < 4; ++n) accO[n] = fzero;
    bf16x8 ap[3];
    #pragma unroll
    for (int ks = 0; ks < 3; ++ks)
        ap[ks] = *(const bf16x8*)&pl[w][cl][ks * 32 + q * 8];
    #pragma unroll
    for (int n = 0; n < 4; ++n)
        #pragma unroll
        for (int ks = 0; ks < 3; ++ks) {
            bf16x8 bv8 = *(const bf16x8*)&vt[n * 16 + cl][ks * 32 + q * 8];
            accO[n] = __builtin_amdgcn_mfma_f32_16x16x32_bf16(ap[ks], bv8, accO[n], 0, 0, 0);
        }

    // ---- 6. normalize rows, pool over the wave's 16 queries, LDS reduce --
    float rcp4[4];
    #pragma unroll
    for (int r = 0; r < 4; ++r) rcp4[r] = 1.0f / l4[r];
    #pragma unroll
    for (int n = 0; n < 4; ++n) {
        float pp = 0.f;
        #pragma unroll
        for (int r = 0; r < 4; ++r) pp += accO[n][r] * rcp4[r];
        pp += __shfl_xor(pp, 16, 64);
        pp += __shfl_xor(pp, 32, 64);
        if (q == 0) pr[w][n * 16 + cl] = pp;
    }
    __syncthreads();
    if (t < 64) {
        long pb = (((long)(b * NH + h) * 32) + blockIdx.x) * 64 + t;
        partial[pb] = pr[0][t] + pr[1][t];
    }
}

// ---------------------------------------------------------------------------
// Kernel 4: out = relu((sum_sblk partial)/S @ Wfc + bfc) -> f32.
// 48 blocks = (batch, col-tile of 32).
// ---------------------------------------------------------------------------
__global__ __launch_bounds__(256) void fc_relu_f(
    const float* __restrict__ partial, const float* __restrict__ Wfc,
    const float* __restrict__ bfc, float* __restrict__ out) {
    __shared__ float red[8][32];
    __shared__ float ps[768];
    const int t = threadIdx.x;
    const int nb = blockIdx.x % 24;     // col tile (32 wide)
    const int bb = blockIdx.x / 24;     // batch

    for (int d = t; d < DM; d += 256) {
        const float* pp = partial + ((long)(bb * NH + (d >> 6)) * 32) * 64 + (d & 63);
        float s = 0.f;
        #pragma unroll
        for (int sb = 0; sb < 32; ++sb) s += pp[sb * 64];
        ps[d] = s;
    }
    __syncthreads();

    const int nn = t & 31;
    const int dg = t >> 5;              // 0..7, 96 d each
    const int n = nb * 32 + nn;
    float s = 0.f;
    for (int d = dg * 96; d < dg * 96 + 96; ++d)
        s += ps[d] * Wfc[(long)d * DM + n];
    red[dg][nn] = s;
    __syncthreads();
    if (t < 32) {
        float sum = red[0][t] + red[1][t] + red[2][t] + red[3][t]
                  + red[4][t] + red[5][t] + red[6][t] + red[7][t];
        sum = sum * (1.0f / (float)S_LEN) + bfc[nb * 32 + t];
        sum = sum > 0.f ? sum : 0.f;
        out[bb * DM + nb * 32 + t] = sum;
    }
}

// ---------------------------------------------------------------------------
extern "C" void kernel_launch(void* const* d_in, const int* in_sizes, int n_in,
                              void* d_out, int out_size, void* d_ws, size_t ws_size,
                              hipStream_t stream) {
    const float* X   = (const float*)d_in[0];
    const float* Wq  = (const float*)d_in[1];
    const float* bq  = (const float*)d_in[2];
    const float* Wk  = (const float*)d_in[3];
    const float* bk  = (const float*)d_in[4];
    const float* Wv  = (const float*)d_in[5];
    const float* bv  = (const float*)d_in[6];
    const float* Wfc = (const float*)d_in[7];
    const float* bfc = (const float*)d_in[8];

    char* ws = (char*)d_ws;
    const size_t SZ_XB = (size_t)M_TOT * DM * 2;              // 3,145,728
    const size_t SZ_WB = (size_t)NQKV * DM * 2;               // 3,538,944
    u16* Xb = (u16*)(ws);
    u16* Wt = (u16*)(ws + SZ_XB);
    u16* Qp = (u16*)(ws + SZ_XB + SZ_WB);
    u16* Kp = (u16*)(ws + 2 * SZ_XB + SZ_WB);
    u16* Vt = (u16*)(ws + 3 * SZ_XB + SZ_WB);
    float* partial = (float*)(ws + 4 * SZ_XB + SZ_WB);        // [2][12][32][64] f32

    prep<<<1200, 256, 0, stream>>>(X, Wq, Wk, Wv, Xb, Wt);

    qkv_gemm_mfma<<<768, 256, 0, stream>>>(
        Xb, Wt, bq, bk, bv, Qp, Kp, Vt);

    attn_pool_mfma<<<dim3(32, NH, BATCH), 128, 0, stream>>>(
        Qp, Kp, Vt, partial);

    fc_relu_f<<<48, 256, 0, stream>>>(partial, Wfc, bfc, (float*)d_out);
}